// Round 13
// baseline (168.490 us; speedup 1.0000x reference)
//
#include <hip/hip_runtime.h>
#include <hip/hip_bf16.h>
#include <math.h>

#define B 16
#define N 600
#define DIM 128
#define HEADS 8
#define DH 32
#define INNER 256
#define D3 384
#define NC_H (D3*INNER)   /* 98304 */
#define NC_O (INNER*DIM)  /* 32768 */

typedef _Float16 f16x8 __attribute__((ext_vector_type(8)));
typedef float    f32x4 __attribute__((ext_vector_type(4)));

// ---------------- ws layout (float offsets) ----------------  ws = 576 MiB
// hh : 10240   (half, [16][768][128] qkvw softmaxed, TRANSPOSED [e][d])
// ow : 1583104 (f32,  [16][256][128])
// ao : 2117632   qh : 4575232(half)  kh : 5804032(half)  vt : 7032832(half)
// t2h: 8343552 (half, [16][384])   s2h: 8346624 (half, [16][256])
// xh : 8348672 (half, [16][600][128])  ends 8963072
// pH : 8963072  (2 x 16 x 98304)   pO : 12108800 (4 x 16 x 32768)  end 14205952

// ---- fused hypernet layers 1+2 (blocks 0..39) + x->fp16 convert (40..295) ----
__global__ __launch_bounds__(256) void k_chain(const float* __restrict__ resolution,
                                               const float* __restrict__ framerate,
                                               const float* __restrict__ W1, const float* __restrict__ b1,
                                               const float* __restrict__ W2, const float* __restrict__ b2,
                                               const float* __restrict__ V1, const float* __restrict__ c1,
                                               const float* __restrict__ V2, const float* __restrict__ c2,
                                               const float* __restrict__ x,
                                               _Float16* __restrict__ t2h, _Float16* __restrict__ s2h,
                                               _Float16* __restrict__ xh)
{
    __shared__ float fr[B], re[B];
    __shared__ float in_s[B*D3];
    int bid = blockIdx.x, tid = threadIdx.x;
    if (bid >= 40) {        // x -> fp16 (RNE scalar casts), 256 blocks
        const float4* x4 = (const float4*)x;
        uint2* xo = (uint2*)xh;
        for (int i = (bid - 40)*256 + tid; i < B*N*DIM/4; i += 256*256) {
            float4 v = x4[i];
            union { _Float16 h[4]; uint2 u; } pk;
            pk.h[0] = (_Float16)v.x; pk.h[1] = (_Float16)v.y;
            pk.h[2] = (_Float16)v.z; pk.h[3] = (_Float16)v.w;
            xo[i] = pk.u;
        }
        return;
    }
    if (tid < B) { fr[tid] = framerate[tid]; re[tid] = resolution[tid]; }
    __syncthreads();
    if (bid < 24) {
        for (int i = tid; i < B*D3; i += 256) {
            int b = i / D3, j = i - b*D3;
            in_s[i] = fr[b]*W1[j] + re[b]*W1[D3 + j] + b1[j];
        }
        __syncthreads();
        int flat = bid*256 + tid;           // = b*384 + j
        int b = flat / D3, j = flat - b*D3;
        float acc = b2[j];
        #pragma unroll 4
        for (int kk = 0; kk < D3; ++kk)
            acc = fmaf(in_s[b*D3 + kk], W2[kk*D3 + j], acc);
        t2h[flat] = (_Float16)acc;
    } else {
        for (int i = tid; i < B*INNER; i += 256) {
            int b = i >> 8, j = i & 255;
            in_s[i] = fr[b]*V1[j] + re[b]*V1[INNER + j] + c1[j];
        }
        __syncthreads();
        int flat = (bid - 24)*256 + tid;    // = b*256 + j
        int b = flat >> 8, j = flat & 255;
        float acc = c2[j];
        #pragma unroll 4
        for (int kk = 0; kk < INNER; ++kk)
            acc = fmaf(in_s[b*INNER + kk], V2[kk*INNER + j], acc);
        s2h[flat] = (_Float16)acc;
    }
}

static __device__ inline unsigned pk2(float a, float b) {
    auto t = __builtin_amdgcn_cvt_pkrtz(a, b);   // __fp16 ext_vector(2)
    return __builtin_bit_cast(unsigned, t);
}

// MFMA hypernet GEMM: wave = 64 cols, B-frags gathered from global f32 W
// (dword), cvt_pkrtz -> f16x8, mfma 16x16x32, no LDS/barriers, 2-deep pipeline.
#define LOADT(S, t) \
    _Pragma("unroll") for (int cc = 0; cc < 4; ++cc) { \
        _Pragma("unroll") for (int j = 0; j < 8; ++j) \
            S[cc*8+j] = Wp[(size_t)((t)*32 + g*8 + j)*NC + cc*16]; }

#define COMPT(S, t) \
    _Pragma("unroll") for (int cc = 0; cc < 4; ++cc) { \
        union { unsigned u[4]; f16x8 v; } bf; \
        bf.u[0] = pk2(S[cc*8+0], S[cc*8+1]); \
        bf.u[1] = pk2(S[cc*8+2], S[cc*8+3]); \
        bf.u[2] = pk2(S[cc*8+4], S[cc*8+5]); \
        bf.u[3] = pk2(S[cc*8+6], S[cc*8+7]); \
        acc[cc] = __builtin_amdgcn_mfma_f32_16x16x32_f16(af[(t)], bf.v, acc[cc], 0, 0, 0); }

template<int K, int NC, int KSG>
__device__ __forceinline__ void hgemm_body(int bidl, int tid,
                                           const _Float16* __restrict__ th,
                                           const float* __restrict__ W,
                                           float* __restrict__ partial)
{
    constexpr int KR = K / KSG;       // 192 (W3) or 64 (V3)
    constexpr int TILES = KR / 32;    // 6 or 2 (even)
    constexpr int NCB = NC / 256;
    int w = tid >> 6, lane = tid & 63;
    int ql = lane & 15, g = lane >> 4;
    int cb = bidl % NCB, ksg = bidl / NCB;
    int colbase = cb*256 + w*64;
    const float* Wp = W + (size_t)(ksg*KR)*NC + colbase + ql;

    f16x8 af[TILES];
    #pragma unroll
    for (int t = 0; t < TILES; ++t)
        af[t] = *(const f16x8*)(th + ql*K + ksg*KR + t*32 + g*8);

    f32x4 acc[4];
    #pragma unroll
    for (int cc = 0; cc < 4; ++cc) acc[cc] = (f32x4){0.f, 0.f, 0.f, 0.f};

    float sA[32], sB[32];
    LOADT(sA, 0)
    LOADT(sB, 1)
    #pragma unroll
    for (int t = 0; t < TILES; t += 2) {
        COMPT(sA, t)
        if (t + 2 < TILES) LOADT(sA, t+2)
        COMPT(sB, t+1)
        if (t + 3 < TILES) LOADT(sB, t+3)
    }

    float* pp = partial + (size_t)ksg*B*NC + colbase + ql;
    #pragma unroll
    for (int cc = 0; cc < 4; ++cc)
        #pragma unroll
        for (int r = 0; r < 4; ++r)
            pp[(size_t)(4*g + r)*NC + cc*16] = acc[cc][r];
}

#define NBH ((NC_H/256)*2)   /* 768 */
#define NBO ((NC_O/256)*4)   /* 512 */

__global__ __launch_bounds__(256) void k_hgemm_all(const _Float16* __restrict__ t2h,
                                                   const _Float16* __restrict__ s2h,
                                                   const float* __restrict__ W3,
                                                   const float* __restrict__ V3,
                                                   float* __restrict__ pH,
                                                   float* __restrict__ pO)
{
    int bid = blockIdx.x, tid = threadIdx.x;
    if (bid < NBH) hgemm_body<D3, NC_H, 2>(bid, tid, t2h, W3, pH);
    else           hgemm_body<INNER, NC_O, 4>(bid - NBH, tid, s2h, V3, pO);
}

// ---- fused split-K reduce + bias + column softmax (optional transposed fp16 out) ----
template<int R, int CPB, int COLS, int GROUPS, int KSG, int NC, bool TR, typename OT>
__device__ __forceinline__ void smred_body(int bidl, int tid,
                                           const float* __restrict__ partial,
                                           const float* __restrict__ bias,
                                           OT* __restrict__ outp,
                                           float* __restrict__ red)
{
    constexpr int RPT = R / GROUPS;
    int col = tid % COLS, g = tid / COLS;
    constexpr int nb = CPB / COLS;
    int b = bidl / nb, cb = bidl % nb;
    int e = cb*COLS + col;
    float vals[RPT];
    float m = -1e30f;
    #pragma unroll 4
    for (int r = 0; r < RPT; ++r) {
        int flat = (g*RPT + r)*CPB + e;
        float s = bias[flat];
        #pragma unroll
        for (int ks = 0; ks < KSG; ++ks)
            s += partial[(size_t)ks*B*NC + (size_t)b*NC + flat];
        vals[r] = s;
        m = fmaxf(m, s);
    }
    red[g*COLS + col] = m;
    __syncthreads();
    float M = red[col];
    #pragma unroll
    for (int gg = 1; gg < GROUPS; ++gg) M = fmaxf(M, red[gg*COLS + col]);
    __syncthreads();
    float s = 0.f;
    #pragma unroll 4
    for (int r = 0; r < RPT; ++r) { vals[r] = __expf(vals[r] - M); s += vals[r]; }
    red[g*COLS + col] = s;
    __syncthreads();
    float S = 0.f;
    #pragma unroll
    for (int gg = 0; gg < GROUPS; ++gg) S += red[gg*COLS + col];
    float inv = 1.f / S;
    #pragma unroll 4
    for (int r = 0; r < RPT; ++r) {
        if constexpr (TR)
            outp[(size_t)b*NC + (size_t)e*R + (g*RPT + r)] = (OT)(vals[r] * inv);
        else
            outp[(size_t)b*NC + (size_t)(g*RPT + r)*CPB + e] = (OT)(vals[r] * inv);
    }
}

#define NSH (B*24)   /* 384: h path  (R=128 over d, CPB=768) -> hh fp16 [e][d] */
#define NSO (B*8)    /* 128: ow path (R=256 over e, CPB=128) -> ow f32 */

__global__ __launch_bounds__(256) void k_smred(const float* __restrict__ pH,
                                               const float* __restrict__ pO,
                                               const float* __restrict__ b3,
                                               const float* __restrict__ c3,
                                               _Float16* __restrict__ hh,
                                               float* __restrict__ ow)
{
    __shared__ float red[256];
    int bid = blockIdx.x, tid = threadIdx.x;
    if (bid < NSH) smred_body<DIM, 3*INNER, 32, 8, 2, NC_H, true, _Float16>(bid, tid, pH, b3, hh, red);
    else           smred_body<INNER, DIM, 16, 16, 4, NC_O, false, float>(bid - NSH, tid, pO, c3, ow, red);
}

// ---- MFMA projection (unchanged from round 12) ----
__global__ __launch_bounds__(256) void k_projm(const _Float16* __restrict__ xh,
                                               const _Float16* __restrict__ hh,
                                               _Float16* __restrict__ qh,
                                               _Float16* __restrict__ kh,
                                               _Float16* __restrict__ vt)
{
    int bid = blockIdx.x;               // 16 b x 38 chunks
    int b = bid / 38, cn = bid % 38;
    int n0 = cn * 16;
    int tid = threadIdx.x;
    int w = tid >> 6, lane = tid & 63;
    int ql = lane & 15, g = lane >> 4;

    const _Float16* xb = xh + (size_t)b*N*DIM;
    const _Float16* hb = hh + (size_t)b*NC_H;

    int nl = n0 + ql; if (nl > 599) nl = 599;
    f16x8 xf[4];
    #pragma unroll
    for (int kt = 0; kt < 4; ++kt)
        xf[kt] = *(const f16x8*)(xb + (size_t)nl*DIM + kt*32 + g*8);

    const float scale = 0.17677669529663687f;   // 32^-0.5 folded into q
    #pragma unroll
    for (int j = 0; j < 12; ++j) {
        int ct = w*12 + j;              // 0..47
        int type = ct >> 4;             // 0=q, 1=k, 2=v
        int e0 = (ct & 15) * 16;        // col base within its 256-group
        f16x8 wf[4];
        #pragma unroll
        for (int kt = 0; kt < 4; ++kt)
            wf[kt] = *(const f16x8*)(hb + (size_t)(ct*16 + ql)*DIM + kt*32 + g*8);
        f32x4 acc = (f32x4){0.f, 0.f, 0.f, 0.f};
        if (type == 2) {
            #pragma unroll
            for (int kt = 0; kt < 4; ++kt)
                acc = __builtin_amdgcn_mfma_f32_16x16x32_f16(wf[kt], xf[kt], acc, 0, 0, 0);
            int n = n0 + ql;
            if (n < 600) {
                #pragma unroll
                for (int r = 0; r < 4; ++r) {
                    int e = e0 + 4*g + r;
                    vt[((size_t)(b*HEADS + (e>>5))*DH + (e&31))*640 + n] = (_Float16)acc[r];
                }
            }
        } else {
            #pragma unroll
            for (int kt = 0; kt < 4; ++kt)
                acc = __builtin_amdgcn_mfma_f32_16x16x32_f16(xf[kt], wf[kt], acc, 0, 0, 0);
            int e = e0 + ql;
            int head = e >> 5, dh = e & 31;
            _Float16* dst = (type == 0 ? qh : kh);
            float scl = (type == 0) ? scale : 1.f;
            #pragma unroll
            for (int r = 0; r < 4; ++r) {
                int n = n0 + 4*g + r;
                if (n < 600)
                    dst[((size_t)(b*HEADS + head)*N + n)*DH + dh] = (_Float16)(acc[r]*scl);
            }
        }
    }
    // vt tail cols 600..639: zero-fill (0*NaN = NaN hazard in PV otherwise)
    if (cn == 37) {
        _Float16* vp = vt + ((size_t)b*256 + tid)*640;
        #pragma unroll
        for (int c = 600; c < 640; ++c) vp[c] = (_Float16)0.f;
    }
}

// MFMA flash attention v5.  Block = 8 waves = ALL 8 heads of one (b, q-chunk);
// mask tile [16][64] staged ONCE per block (waves 0-3), double-buffered.
// Grid bid = qc*16 + b -> bid%8 = b%8: all 38 qc-blocks sharing K/V+mask stay
// in one XCD class (K/V ~0.6MB/b, L2-resident).
__global__ __launch_bounds__(512) void k_attn5(const _Float16* __restrict__ qh,
                                               const _Float16* __restrict__ kh,
                                               const _Float16* __restrict__ vt,
                                               const float* __restrict__ mask,
                                               float* __restrict__ ao)
{
    __shared__ float mbuf[2][16][65];
    __shared__ __align__(16) _Float16 plds[8][16][72];
    int bid = blockIdx.x;
    int qc = bid / 16, b = bid % 16;
    int tid = threadIdx.x;
    int w = tid >> 6, lane = tid & 63;
    int ql = lane & 15, g = lane >> 4;
    int h = w;                          // 8 waves = 8 heads
    int q0 = qc*16;
    size_t bh = (size_t)(b*HEADS + h);
    const _Float16* Qb  = qh + bh*(size_t)(N*DH);
    const _Float16* Kb  = kh + bh*(size_t)(N*DH);
    const _Float16* Vtb = vt + bh*(size_t)(DH*640);

    int qrow = q0 + ql;
    int qr = qrow > 599 ? 599 : qrow;
    f16x8 qf = *(const f16x8*)(Qb + (size_t)qr*DH + g*8);

    bool stager = (w < 4);
    int rl = (w & 3)*4 + (lane >> 4);    // local tile row 0..15 (stagers)
    int mcol = (lane & 15)*4;            // float col 0..60
    int mgr = q0 + rl; if (mgr > 599) mgr = 599;
    const float* mgp = mask + ((size_t)b*N + mgr)*N;

    float M = -1e30f, S = 0.f;
    f32x4 acc[2];
    acc[0] = (f32x4){0.f,0.f,0.f,0.f};
    acc[1] = (f32x4){0.f,0.f,0.f,0.f};

    if (stager) {
        int c0 = mcol; if (c0 > 596) c0 = 596;
        float4 mv = *(const float4*)(mgp + c0);
        mbuf[0][rl][mcol+0] = mv.x;
        mbuf[0][rl][mcol+1] = mv.y;
        mbuf[0][rl][mcol+2] = mv.z;
        mbuf[0][rl][mcol+3] = mv.w;
    }
    __syncthreads();

    for (int c = 0; c < 10; ++c) {
        int k0 = c*64;
        int cur = c & 1;
        float4 mnext;
        if (stager && c < 9) {          // issue next tile's load before compute
            int cg = (c+1)*64 + mcol; if (cg > 596) cg = 596;
            mnext = *(const float4*)(mgp + cg);
        }
        f32x4 st[4];
        #pragma unroll
        for (int t = 0; t < 4; ++t) {
            int kr = k0 + 16*t + ql; if (kr > 599) kr = 599;
            f16x8 kf = *(const f16x8*)(Kb + (size_t)kr*DH + g*8);
            st[t] = __builtin_amdgcn_mfma_f32_16x16x32_f16(
                kf, qf, (f32x4){0.f,0.f,0.f,0.f}, 0, 0, 0);
        }
        float tm = -1e30f;
        #pragma unroll
        for (int t = 0; t < 4; ++t) {
            #pragma unroll
            for (int r = 0; r < 4; ++r) {
                int key = k0 + 16*t + 4*g + r;
                float sv = st[t][r];
                if (key >= N) sv = -1e30f;
                st[t][r] = sv;
                tm = fmaxf(tm, sv);
            }
        }
        tm = fmaxf(tm, __shfl_xor(tm, 16));
        tm = fmaxf(tm, __shfl_xor(tm, 32));
        float Mn = fmaxf(M, tm);
        float scl = __expf(M - Mn);
        M = Mn;
        S *= scl;
        acc[0] *= scl;
        acc[1] *= scl;
        float ssum = 0.f;
        #pragma unroll
        for (int t = 0; t < 4; ++t) {
            int cb4 = 16*t + 4*g;
            float e0 = __expf(st[t][0] - Mn);
            float e1 = __expf(st[t][1] - Mn);
            float e2 = __expf(st[t][2] - Mn);
            float e3 = __expf(st[t][3] - Mn);
            ssum += (e0 + e1) + (e2 + e3);
            float m0 = mbuf[cur][ql][cb4+0];
            float m1 = mbuf[cur][ql][cb4+1];
            float m2 = mbuf[cur][ql][cb4+2];
            float m3 = mbuf[cur][ql][cb4+3];
            *(unsigned*)&plds[w][ql][cb4]     = pk2(e0*m0, e1*m1);
            *(unsigned*)&plds[w][ql][cb4 + 2] = pk2(e2*m2, e3*m3);
        }
        ssum += __shfl_xor(ssum, 16);
        ssum += __shfl_xor(ssum, 32);
        S += ssum;
        #pragma unroll
        for (int win = 0; win < 2; ++win) {
            f16x8 pf = *(const f16x8*)&plds[w][ql][win*32 + g*8];
            #pragma unroll
            for (int dt = 0; dt < 2; ++dt) {
                f16x8 vf = *(const f16x8*)(Vtb + (size_t)(dt*16 + ql)*640 + k0 + win*32 + g*8);
                acc[dt] = __builtin_amdgcn_mfma_f32_16x16x32_f16(vf, pf, acc[dt], 0, 0, 0);
            }
        }
        if (stager && c < 9) {
            int nb = cur ^ 1;
            mbuf[nb][rl][mcol+0] = mnext.x;
            mbuf[nb][rl][mcol+1] = mnext.y;
            mbuf[nb][rl][mcol+2] = mnext.z;
            mbuf[nb][rl][mcol+3] = mnext.w;
        }
        __syncthreads();
    }

    if (qrow < N) {
        float inv = 1.f / S;
        float* o = ao + ((size_t)b*N + qrow)*INNER + h*DH;
        #pragma unroll
        for (int dt = 0; dt < 2; ++dt)
            #pragma unroll
            for (int r = 0; r < 4; ++r)
                o[dt*16 + 4*g + r] = acc[dt][r] * inv;
    }
}

__global__ __launch_bounds__(128) void k_final(const float* __restrict__ ao,
                                               const float* __restrict__ ow,
                                               float* __restrict__ out)
{
    __shared__ float4 os4[6*64];
    int b = blockIdx.x / 100, t0 = (blockIdx.x % 100)*6;
    int tid = threadIdx.x;
    const float4* ap4 = (const float4*)(ao + ((size_t)b*N + t0)*INNER);
    for (int i = tid; i < 6*64; i += 128) os4[i] = ap4[i];
    __syncthreads();
    float acc[6];
    #pragma unroll
    for (int r = 0; r < 6; ++r) acc[r] = 0.f;
    const float* wp = ow + (size_t)b*NC_O + tid;
    for (int i4 = 0; i4 < 64; ++i4) {
        float w0 = wp[(size_t)(4*i4)*DIM];
        float w1 = wp[(size_t)(4*i4+1)*DIM];
        float w2 = wp[(size_t)(4*i4+2)*DIM];
        float w3 = wp[(size_t)(4*i4+3)*DIM];
        #pragma unroll
        for (int r = 0; r < 6; ++r) {
            float4 av = os4[r*64 + i4];
            acc[r] = fmaf(av.x, w0, fmaf(av.y, w1, fmaf(av.z, w2, fmaf(av.w, w3, acc[r]))));
        }
    }
    float* op = out + ((size_t)b*N + t0)*DIM + tid;
    #pragma unroll
    for (int r = 0; r < 6; ++r) op[r*DIM] = acc[r];
}

extern "C" void kernel_launch(void* const* d_in, const int* in_sizes, int n_in,
                              void* d_out, int out_size, void* d_ws, size_t ws_size,
                              hipStream_t stream)
{
    const float* x          = (const float*)d_in[0];
    const float* mask       = (const float*)d_in[1];
    const float* resolution = (const float*)d_in[2];
    const float* framerate  = (const float*)d_in[3];
    const float* W1 = (const float*)d_in[4];
    const float* b1 = (const float*)d_in[5];
    const float* W2 = (const float*)d_in[6];
    const float* b2 = (const float*)d_in[7];
    const float* W3 = (const float*)d_in[8];
    const float* b3 = (const float*)d_in[9];
    const float* V1 = (const float*)d_in[10];
    const float* c1 = (const float*)d_in[11];
    const float* V2 = (const float*)d_in[12];
    const float* c2 = (const float*)d_in[13];
    const float* V3 = (const float*)d_in[14];
    const float* c3 = (const float*)d_in[15];

    float* ws = (float*)d_ws;
    _Float16* hh  = (_Float16*)(ws + 10240);     // [16][768][128]
    float* ow  = ws + 1583104;
    float* ao  = ws + 2117632;
    _Float16* qh  = (_Float16*)(ws + 4575232);
    _Float16* kh  = (_Float16*)(ws + 5804032);
    _Float16* vt  = (_Float16*)(ws + 7032832);
    _Float16* t2h = (_Float16*)(ws + 8343552);   // [16][384]
    _Float16* s2h = (_Float16*)(ws + 8346624);   // [16][256]
    _Float16* xh  = (_Float16*)(ws + 8348672);   // [16][600][128]
    float* pH  = ws + 8963072;              // 2 x 1,572,864
    float* pO  = ws + 12108800;             // 4 x 524,288
    float* out = (float*)d_out;

    hipLaunchKernelGGL(k_chain, dim3(296), dim3(256), 0, stream,
                       resolution, framerate, W1, b1, W2, b2, V1, c1, V2, c2,
                       x, t2h, s2h, xh);
    hipLaunchKernelGGL(k_hgemm_all, dim3(NBH + NBO), dim3(256), 0, stream,
                       t2h, s2h, W3, V3, pH, pO);
    hipLaunchKernelGGL(k_smred, dim3(NSH + NSO), dim3(256), 0, stream,
                       pH, pO, b3, c3, hh, ow);
    hipLaunchKernelGGL(k_projm, dim3(B*38), dim3(256), 0, stream,
                       xh, hh, qh, kh, vt);
    hipLaunchKernelGGL(k_attn5, dim3(38*16), dim3(512), 0, stream, qh, kh, vt, mask, ao);
    hipLaunchKernelGGL(k_final, dim3(B*100), dim3(128), 0, stream, ao, ow, out);
}

// Round 14
// 160.755 us; speedup vs baseline: 1.0481x; 1.0481x over previous
//
#include <hip/hip_runtime.h>
#include <hip/hip_bf16.h>
#include <math.h>

#define B 16
#define N 600
#define DIM 128
#define HEADS 8
#define DH 32
#define INNER 256
#define D3 384
#define NC_H (D3*INNER)   /* 98304 */
#define NC_O (INNER*DIM)  /* 32768 */

typedef _Float16 f16x8 __attribute__((ext_vector_type(8)));
typedef float    f32x4 __attribute__((ext_vector_type(4)));

// ---------------- ws layout (float offsets) ----------------  ws = 576 MiB
// hh : 10240   (half, [16][768][128] qkvw softmaxed, TRANSPOSED [e][d])
// ow : 1583104 (f32,  [16][256][128])
// ao : 2117632   qh : 4575232(half)  kh : 5804032(half)  vt : 7032832(half)
// t2h: 8343552 (half, [16][384])   s2h: 8346624 (half, [16][256])
// pH : 8963072  (2 x 16 x 98304)   pO : 12108800 (4 x 16 x 32768)  end 14205952

// ---- fused hypernet layers 1+2 ----
__global__ __launch_bounds__(256) void k_chain(const float* __restrict__ resolution,
                                               const float* __restrict__ framerate,
                                               const float* __restrict__ W1, const float* __restrict__ b1,
                                               const float* __restrict__ W2, const float* __restrict__ b2,
                                               const float* __restrict__ V1, const float* __restrict__ c1,
                                               const float* __restrict__ V2, const float* __restrict__ c2,
                                               _Float16* __restrict__ t2h, _Float16* __restrict__ s2h)
{
    __shared__ float fr[B], re[B];
    __shared__ float in_s[B*D3];
    int bid = blockIdx.x, tid = threadIdx.x;
    if (tid < B) { fr[tid] = framerate[tid]; re[tid] = resolution[tid]; }
    __syncthreads();
    if (bid < 24) {
        for (int i = tid; i < B*D3; i += 256) {
            int b = i / D3, j = i - b*D3;
            in_s[i] = fr[b]*W1[j] + re[b]*W1[D3 + j] + b1[j];
        }
        __syncthreads();
        int flat = bid*256 + tid;           // = b*384 + j
        int b = flat / D3, j = flat - b*D3;
        float acc = b2[j];
        #pragma unroll 4
        for (int kk = 0; kk < D3; ++kk)
            acc = fmaf(in_s[b*D3 + kk], W2[kk*D3 + j], acc);
        t2h[flat] = (_Float16)acc;
    } else {
        for (int i = tid; i < B*INNER; i += 256) {
            int b = i >> 8, j = i & 255;
            in_s[i] = fr[b]*V1[j] + re[b]*V1[INNER + j] + c1[j];
        }
        __syncthreads();
        int flat = (bid - 24)*256 + tid;    // = b*256 + j
        int b = flat >> 8, j = flat & 255;
        float acc = c2[j];
        #pragma unroll 4
        for (int kk = 0; kk < INNER; ++kk)
            acc = fmaf(in_s[b*INNER + kk], V2[kk*INNER + j], acc);
        s2h[flat] = (_Float16)acc;
    }
}

static __device__ inline unsigned pk2(float a, float b) {
    auto t = __builtin_amdgcn_cvt_pkrtz(a, b);   // __fp16 ext_vector(2)
    return __builtin_bit_cast(unsigned, t);
}

// MFMA hypernet GEMM: wave = 64 cols, B-frags gathered from global f32 W
// (dword), cvt_pkrtz -> f16x8, mfma 16x16x32, no LDS/barriers, 2-deep pipeline.
#define LOADT(S, t) \
    _Pragma("unroll") for (int cc = 0; cc < 4; ++cc) { \
        _Pragma("unroll") for (int j = 0; j < 8; ++j) \
            S[cc*8+j] = Wp[(size_t)((t)*32 + g*8 + j)*NC + cc*16]; }

#define COMPT(S, t) \
    _Pragma("unroll") for (int cc = 0; cc < 4; ++cc) { \
        union { unsigned u[4]; f16x8 v; } bf; \
        bf.u[0] = pk2(S[cc*8+0], S[cc*8+1]); \
        bf.u[1] = pk2(S[cc*8+2], S[cc*8+3]); \
        bf.u[2] = pk2(S[cc*8+4], S[cc*8+5]); \
        bf.u[3] = pk2(S[cc*8+6], S[cc*8+7]); \
        acc[cc] = __builtin_amdgcn_mfma_f32_16x16x32_f16(af[(t)], bf.v, acc[cc], 0, 0, 0); }

template<int K, int NC, int KSG>
__device__ __forceinline__ void hgemm_body(int bidl, int tid,
                                           const _Float16* __restrict__ th,
                                           const float* __restrict__ W,
                                           float* __restrict__ partial)
{
    constexpr int KR = K / KSG;       // 192 (W3) or 64 (V3)
    constexpr int TILES = KR / 32;    // 6 or 2 (even)
    constexpr int NCB = NC / 256;
    int w = tid >> 6, lane = tid & 63;
    int ql = lane & 15, g = lane >> 4;
    int cb = bidl % NCB, ksg = bidl / NCB;
    int colbase = cb*256 + w*64;
    const float* Wp = W + (size_t)(ksg*KR)*NC + colbase + ql;

    f16x8 af[TILES];
    #pragma unroll
    for (int t = 0; t < TILES; ++t)
        af[t] = *(const f16x8*)(th + ql*K + ksg*KR + t*32 + g*8);

    f32x4 acc[4];
    #pragma unroll
    for (int cc = 0; cc < 4; ++cc) acc[cc] = (f32x4){0.f, 0.f, 0.f, 0.f};

    float sA[32], sB[32];
    LOADT(sA, 0)
    LOADT(sB, 1)
    #pragma unroll
    for (int t = 0; t < TILES; t += 2) {
        COMPT(sA, t)
        if (t + 2 < TILES) LOADT(sA, t+2)
        COMPT(sB, t+1)
        if (t + 3 < TILES) LOADT(sB, t+3)
    }

    float* pp = partial + (size_t)ksg*B*NC + colbase + ql;
    #pragma unroll
    for (int cc = 0; cc < 4; ++cc)
        #pragma unroll
        for (int r = 0; r < 4; ++r)
            pp[(size_t)(4*g + r)*NC + cc*16] = acc[cc][r];
}

#define NBH ((NC_H/256)*2)   /* 768 */
#define NBO ((NC_O/256)*4)   /* 512 */

__global__ __launch_bounds__(256) void k_hgemm_all(const _Float16* __restrict__ t2h,
                                                   const _Float16* __restrict__ s2h,
                                                   const float* __restrict__ W3,
                                                   const float* __restrict__ V3,
                                                   float* __restrict__ pH,
                                                   float* __restrict__ pO)
{
    int bid = blockIdx.x, tid = threadIdx.x;
    if (bid < NBH) hgemm_body<D3, NC_H, 2>(bid, tid, t2h, W3, pH);
    else           hgemm_body<INNER, NC_O, 4>(bid - NBH, tid, s2h, V3, pO);
}

// ---- fused split-K reduce + bias + column softmax (optional transposed fp16 out) ----
template<int R, int CPB, int COLS, int GROUPS, int KSG, int NC, bool TR, typename OT>
__device__ __forceinline__ void smred_body(int bidl, int tid,
                                           const float* __restrict__ partial,
                                           const float* __restrict__ bias,
                                           OT* __restrict__ outp,
                                           float* __restrict__ red)
{
    constexpr int RPT = R / GROUPS;
    int col = tid % COLS, g = tid / COLS;
    constexpr int nb = CPB / COLS;
    int b = bidl / nb, cb = bidl % nb;
    int e = cb*COLS + col;
    float vals[RPT];
    float m = -1e30f;
    #pragma unroll 4
    for (int r = 0; r < RPT; ++r) {
        int flat = (g*RPT + r)*CPB + e;
        float s = bias[flat];
        #pragma unroll
        for (int ks = 0; ks < KSG; ++ks)
            s += partial[(size_t)ks*B*NC + (size_t)b*NC + flat];
        vals[r] = s;
        m = fmaxf(m, s);
    }
    red[g*COLS + col] = m;
    __syncthreads();
    float M = red[col];
    #pragma unroll
    for (int gg = 1; gg < GROUPS; ++gg) M = fmaxf(M, red[gg*COLS + col]);
    __syncthreads();
    float s = 0.f;
    #pragma unroll 4
    for (int r = 0; r < RPT; ++r) { vals[r] = __expf(vals[r] - M); s += vals[r]; }
    red[g*COLS + col] = s;
    __syncthreads();
    float S = 0.f;
    #pragma unroll
    for (int gg = 0; gg < GROUPS; ++gg) S += red[gg*COLS + col];
    float inv = 1.f / S;
    #pragma unroll 4
    for (int r = 0; r < RPT; ++r) {
        if constexpr (TR)
            outp[(size_t)b*NC + (size_t)e*R + (g*RPT + r)] = (OT)(vals[r] * inv);
        else
            outp[(size_t)b*NC + (size_t)(g*RPT + r)*CPB + e] = (OT)(vals[r] * inv);
    }
}

#define NSH (B*24)   /* 384: h path  (R=128 over d, CPB=768) -> hh fp16 [e][d] */
#define NSO (B*8)    /* 128: ow path (R=256 over e, CPB=128) -> ow f32 */

__global__ __launch_bounds__(256) void k_smred(const float* __restrict__ pH,
                                               const float* __restrict__ pO,
                                               const float* __restrict__ b3,
                                               const float* __restrict__ c3,
                                               _Float16* __restrict__ hh,
                                               float* __restrict__ ow)
{
    __shared__ float red[256];
    int bid = blockIdx.x, tid = threadIdx.x;
    if (bid < NSH) smred_body<DIM, 3*INNER, 32, 8, 2, NC_H, true, _Float16>(bid, tid, pH, b3, hh, red);
    else           smred_body<INNER, DIM, 16, 16, 4, NC_O, false, float>(bid - NSH, tid, pO, c3, ow, red);
}

// ---- MFMA projection; x loaded f32 and converted in-register (RNE) ----
__global__ __launch_bounds__(256) void k_projm(const float* __restrict__ x,
                                               const _Float16* __restrict__ hh,
                                               _Float16* __restrict__ qh,
                                               _Float16* __restrict__ kh,
                                               _Float16* __restrict__ vt)
{
    int bid = blockIdx.x;               // 16 b x 38 chunks
    int b = bid / 38, cn = bid % 38;
    int n0 = cn * 16;
    int tid = threadIdx.x;
    int w = tid >> 6, lane = tid & 63;
    int ql = lane & 15, g = lane >> 4;

    const float* xb = x + (size_t)b*N*DIM;
    const _Float16* hb = hh + (size_t)b*NC_H;

    int nl = n0 + ql; if (nl > 599) nl = 599;
    f16x8 xf[4];
    #pragma unroll
    for (int kt = 0; kt < 4; ++kt) {
        float4 a = *(const float4*)(xb + (size_t)nl*DIM + kt*32 + g*8);
        float4 c = *(const float4*)(xb + (size_t)nl*DIM + kt*32 + g*8 + 4);
        union { _Float16 hv[8]; f16x8 v; } cv;
        cv.hv[0] = (_Float16)a.x; cv.hv[1] = (_Float16)a.y;
        cv.hv[2] = (_Float16)a.z; cv.hv[3] = (_Float16)a.w;
        cv.hv[4] = (_Float16)c.x; cv.hv[5] = (_Float16)c.y;
        cv.hv[6] = (_Float16)c.z; cv.hv[7] = (_Float16)c.w;
        xf[kt] = cv.v;
    }

    const float scale = 0.17677669529663687f;   // 32^-0.5 folded into q
    #pragma unroll
    for (int j = 0; j < 12; ++j) {
        int ct = w*12 + j;              // 0..47
        int type = ct >> 4;             // 0=q, 1=k, 2=v
        int e0 = (ct & 15) * 16;        // col base within its 256-group
        f16x8 wf[4];
        #pragma unroll
        for (int kt = 0; kt < 4; ++kt)
            wf[kt] = *(const f16x8*)(hb + (size_t)(ct*16 + ql)*DIM + kt*32 + g*8);
        f32x4 acc = (f32x4){0.f, 0.f, 0.f, 0.f};
        if (type == 2) {
            #pragma unroll
            for (int kt = 0; kt < 4; ++kt)
                acc = __builtin_amdgcn_mfma_f32_16x16x32_f16(wf[kt], xf[kt], acc, 0, 0, 0);
            int n = n0 + ql;
            if (n < 600) {
                #pragma unroll
                for (int r = 0; r < 4; ++r) {
                    int e = e0 + 4*g + r;
                    vt[((size_t)(b*HEADS + (e>>5))*DH + (e&31))*640 + n] = (_Float16)acc[r];
                }
            }
        } else {
            #pragma unroll
            for (int kt = 0; kt < 4; ++kt)
                acc = __builtin_amdgcn_mfma_f32_16x16x32_f16(xf[kt], wf[kt], acc, 0, 0, 0);
            int e = e0 + ql;
            int head = e >> 5, dh = e & 31;
            _Float16* dst = (type == 0 ? qh : kh);
            float scl = (type == 0) ? scale : 1.f;
            #pragma unroll
            for (int r = 0; r < 4; ++r) {
                int n = n0 + 4*g + r;
                if (n < 600)
                    dst[((size_t)(b*HEADS + head)*N + n)*DH + dh] = (_Float16)(acc[r]*scl);
            }
        }
    }
    // vt tail cols 600..639: zero-fill (0*NaN = NaN hazard in PV otherwise)
    if (cn == 37) {
        _Float16* vp = vt + ((size_t)b*256 + tid)*640;
        #pragma unroll
        for (int c = 600; c < 640; ++c) vp[c] = (_Float16)0.f;
    }
}

// MFMA flash attention v4 (round-12 proven config, reverted from v5).
__global__ __launch_bounds__(256) void k_attn4(const _Float16* __restrict__ qh,
                                               const _Float16* __restrict__ kh,
                                               const _Float16* __restrict__ vt,
                                               const float* __restrict__ mask,
                                               float* __restrict__ ao)
{
    __shared__ float mbuf[2][16][65];
    __shared__ __align__(16) _Float16 plds[4][16][72];
    int bid = blockIdx.x;
    int qc = bid / 32, r2 = bid % 32;
    int b = r2 >> 1, hg = r2 & 1;
    int tid = threadIdx.x;
    int w = tid >> 6, lane = tid & 63;
    int ql = lane & 15, g = lane >> 4;
    int h = hg*4 + w;
    int q0 = qc*16;
    size_t bh = (size_t)(b*HEADS + h);
    const _Float16* Qb  = qh + bh*(size_t)(N*DH);
    const _Float16* Kb  = kh + bh*(size_t)(N*DH);
    const _Float16* Vtb = vt + bh*(size_t)(DH*640);

    int qrow = q0 + ql;
    int qr = qrow > 599 ? 599 : qrow;
    f16x8 qf = *(const f16x8*)(Qb + (size_t)qr*DH + g*8);

    int rl = w*4 + (lane >> 4);
    int mcol = (lane & 15)*4;
    int mgr = q0 + rl; if (mgr > 599) mgr = 599;
    const float* mgp = mask + ((size_t)b*N + mgr)*N;

    float M = -1e30f, S = 0.f;
    f32x4 acc[2];
    acc[0] = (f32x4){0.f,0.f,0.f,0.f};
    acc[1] = (f32x4){0.f,0.f,0.f,0.f};

    {
        int c0 = mcol; if (c0 > 596) c0 = 596;
        float4 mv = *(const float4*)(mgp + c0);
        mbuf[0][rl][mcol+0] = mv.x;
        mbuf[0][rl][mcol+1] = mv.y;
        mbuf[0][rl][mcol+2] = mv.z;
        mbuf[0][rl][mcol+3] = mv.w;
    }
    __syncthreads();

    for (int c = 0; c < 10; ++c) {
        int k0 = c*64;
        int cur = c & 1;
        float4 mnext;
        if (c < 9) {
            int cg = (c+1)*64 + mcol; if (cg > 596) cg = 596;
            mnext = *(const float4*)(mgp + cg);
        }
        f32x4 st[4];
        #pragma unroll
        for (int t = 0; t < 4; ++t) {
            int kr = k0 + 16*t + ql; if (kr > 599) kr = 599;
            f16x8 kf = *(const f16x8*)(Kb + (size_t)kr*DH + g*8);
            st[t] = __builtin_amdgcn_mfma_f32_16x16x32_f16(
                kf, qf, (f32x4){0.f,0.f,0.f,0.f}, 0, 0, 0);
        }
        float tm = -1e30f;
        #pragma unroll
        for (int t = 0; t < 4; ++t) {
            #pragma unroll
            for (int r = 0; r < 4; ++r) {
                int key = k0 + 16*t + 4*g + r;
                float sv = st[t][r];
                if (key >= N) sv = -1e30f;
                st[t][r] = sv;
                tm = fmaxf(tm, sv);
            }
        }
        tm = fmaxf(tm, __shfl_xor(tm, 16));
        tm = fmaxf(tm, __shfl_xor(tm, 32));
        float Mn = fmaxf(M, tm);
        float scl = __expf(M - Mn);
        M = Mn;
        S *= scl;
        acc[0] *= scl;
        acc[1] *= scl;
        float ssum = 0.f;
        #pragma unroll
        for (int t = 0; t < 4; ++t) {
            int cb4 = 16*t + 4*g;
            float e0 = __expf(st[t][0] - Mn);
            float e1 = __expf(st[t][1] - Mn);
            float e2 = __expf(st[t][2] - Mn);
            float e3 = __expf(st[t][3] - Mn);
            ssum += (e0 + e1) + (e2 + e3);
            float m0 = mbuf[cur][ql][cb4+0];
            float m1 = mbuf[cur][ql][cb4+1];
            float m2 = mbuf[cur][ql][cb4+2];
            float m3 = mbuf[cur][ql][cb4+3];
            *(unsigned*)&plds[w][ql][cb4]     = pk2(e0*m0, e1*m1);
            *(unsigned*)&plds[w][ql][cb4 + 2] = pk2(e2*m2, e3*m3);
        }
        ssum += __shfl_xor(ssum, 16);
        ssum += __shfl_xor(ssum, 32);
        S += ssum;
        #pragma unroll
        for (int win = 0; win < 2; ++win) {
            f16x8 pf = *(const f16x8*)&plds[w][ql][win*32 + g*8];
            #pragma unroll
            for (int dt = 0; dt < 2; ++dt) {
                f16x8 vf = *(const f16x8*)(Vtb + (size_t)(dt*16 + ql)*640 + k0 + win*32 + g*8);
                acc[dt] = __builtin_amdgcn_mfma_f32_16x16x32_f16(vf, pf, acc[dt], 0, 0, 0);
            }
        }
        if (c < 9) {
            int nb = cur ^ 1;
            mbuf[nb][rl][mcol+0] = mnext.x;
            mbuf[nb][rl][mcol+1] = mnext.y;
            mbuf[nb][rl][mcol+2] = mnext.z;
            mbuf[nb][rl][mcol+3] = mnext.w;
        }
        __syncthreads();
    }

    if (qrow < N) {
        float inv = 1.f / S;
        float* o = ao + ((size_t)b*N + qrow)*INNER + h*DH;
        #pragma unroll
        for (int dt = 0; dt < 2; ++dt)
            #pragma unroll
            for (int r = 0; r < 4; ++r)
                o[dt*16 + 4*g + r] = acc[dt][r] * inv;
    }
}

__global__ __launch_bounds__(128) void k_final(const float* __restrict__ ao,
                                               const float* __restrict__ ow,
                                               float* __restrict__ out)
{
    __shared__ float4 os4[6*64];
    int b = blockIdx.x / 100, t0 = (blockIdx.x % 100)*6;
    int tid = threadIdx.x;
    const float4* ap4 = (const float4*)(ao + ((size_t)b*N + t0)*INNER);
    for (int i = tid; i < 6*64; i += 128) os4[i] = ap4[i];
    __syncthreads();
    float acc[6];
    #pragma unroll
    for (int r = 0; r < 6; ++r) acc[r] = 0.f;
    const float* wp = ow + (size_t)b*NC_O + tid;
    for (int i4 = 0; i4 < 64; ++i4) {
        float w0 = wp[(size_t)(4*i4)*DIM];
        float w1 = wp[(size_t)(4*i4+1)*DIM];
        float w2 = wp[(size_t)(4*i4+2)*DIM];
        float w3 = wp[(size_t)(4*i4+3)*DIM];
        #pragma unroll
        for (int r = 0; r < 6; ++r) {
            float4 av = os4[r*64 + i4];
            acc[r] = fmaf(av.x, w0, fmaf(av.y, w1, fmaf(av.z, w2, fmaf(av.w, w3, acc[r]))));
        }
    }
    float* op = out + ((size_t)b*N + t0)*DIM + tid;
    #pragma unroll
    for (int r = 0; r < 6; ++r) op[r*DIM] = acc[r];
}

extern "C" void kernel_launch(void* const* d_in, const int* in_sizes, int n_in,
                              void* d_out, int out_size, void* d_ws, size_t ws_size,
                              hipStream_t stream)
{
    const float* x          = (const float*)d_in[0];
    const float* mask       = (const float*)d_in[1];
    const float* resolution = (const float*)d_in[2];
    const float* framerate  = (const float*)d_in[3];
    const float* W1 = (const float*)d_in[4];
    const float* b1 = (const float*)d_in[5];
    const float* W2 = (const float*)d_in[6];
    const float* b2 = (const float*)d_in[7];
    const float* W3 = (const float*)d_in[8];
    const float* b3 = (const float*)d_in[9];
    const float* V1 = (const float*)d_in[10];
    const float* c1 = (const float*)d_in[11];
    const float* V2 = (const float*)d_in[12];
    const float* c2 = (const float*)d_in[13];
    const float* V3 = (const float*)d_in[14];
    const float* c3 = (const float*)d_in[15];

    float* ws = (float*)d_ws;
    _Float16* hh  = (_Float16*)(ws + 10240);     // [16][768][128]
    float* ow  = ws + 1583104;
    float* ao  = ws + 2117632;
    _Float16* qh  = (_Float16*)(ws + 4575232);
    _Float16* kh  = (_Float16*)(ws + 5804032);
    _Float16* vt  = (_Float16*)(ws + 7032832);
    _Float16* t2h = (_Float16*)(ws + 8343552);   // [16][384]
    _Float16* s2h = (_Float16*)(ws + 8346624);   // [16][256]
    float* pH  = ws + 8963072;              // 2 x 1,572,864
    float* pO  = ws + 12108800;             // 4 x 524,288
    float* out = (float*)d_out;

    hipLaunchKernelGGL(k_chain, dim3(40), dim3(256), 0, stream,
                       resolution, framerate, W1, b1, W2, b2, V1, c1, V2, c2,
                       t2h, s2h);
    hipLaunchKernelGGL(k_hgemm_all, dim3(NBH + NBO), dim3(256), 0, stream,
                       t2h, s2h, W3, V3, pH, pO);
    hipLaunchKernelGGL(k_smred, dim3(NSH + NSO), dim3(256), 0, stream,
                       pH, pO, b3, c3, hh, ow);
    hipLaunchKernelGGL(k_projm, dim3(B*38), dim3(256), 0, stream,
                       x, hh, qh, kh, vt);
    hipLaunchKernelGGL(k_attn4, dim3(38*32), dim3(256), 0, stream, qh, kh, vt, mask, ao);
    hipLaunchKernelGGL(k_final, dim3(B*100), dim3(128), 0, stream, ao, ow, out);
}

// Round 15
// 159.598 us; speedup vs baseline: 1.0557x; 1.0072x over previous
//
#include <hip/hip_runtime.h>
#include <hip/hip_bf16.h>
#include <math.h>

#define B 16
#define N 600
#define DIM 128
#define HEADS 8
#define DH 32
#define INNER 256
#define D3 384
#define NC_H (D3*INNER)   /* 98304 */
#define NC_O (INNER*DIM)  /* 32768 */

typedef _Float16 f16x8 __attribute__((ext_vector_type(8)));
typedef float    f32x4 __attribute__((ext_vector_type(4)));

// ---------------- ws layout (float offsets) ----------------  ws = 576 MiB
// hh : 10240   (half, [16][768][128] qkvw softmaxed, TRANSPOSED [e][d])
// ow : 1583104 (f32,  [16][256][128])
// ao : 2117632 (half, [16][600][256])
// qh : 4575232(half)  kh : 5804032(half)  vt : 7032832(half)
// t2h: 8343552 (half, [16][384])   s2h: 8346624 (half, [16][256])
// pH : 8963072  (2 x 16 x 98304)   pO : 12108800 (4 x 16 x 32768)  end 14205952

// ---- fused hypernet layers 1+2 ----
__global__ __launch_bounds__(256) void k_chain(const float* __restrict__ resolution,
                                               const float* __restrict__ framerate,
                                               const float* __restrict__ W1, const float* __restrict__ b1,
                                               const float* __restrict__ W2, const float* __restrict__ b2,
                                               const float* __restrict__ V1, const float* __restrict__ c1,
                                               const float* __restrict__ V2, const float* __restrict__ c2,
                                               _Float16* __restrict__ t2h, _Float16* __restrict__ s2h)
{
    __shared__ float fr[B], re[B];
    __shared__ float in_s[B*D3];
    int bid = blockIdx.x, tid = threadIdx.x;
    if (tid < B) { fr[tid] = framerate[tid]; re[tid] = resolution[tid]; }
    __syncthreads();
    if (bid < 24) {
        for (int i = tid; i < B*D3; i += 256) {
            int b = i / D3, j = i - b*D3;
            in_s[i] = fr[b]*W1[j] + re[b]*W1[D3 + j] + b1[j];
        }
        __syncthreads();
        int flat = bid*256 + tid;           // = b*384 + j
        int b = flat / D3, j = flat - b*D3;
        float acc = b2[j];
        #pragma unroll 4
        for (int kk = 0; kk < D3; ++kk)
            acc = fmaf(in_s[b*D3 + kk], W2[kk*D3 + j], acc);
        t2h[flat] = (_Float16)acc;
    } else {
        for (int i = tid; i < B*INNER; i += 256) {
            int b = i >> 8, j = i & 255;
            in_s[i] = fr[b]*V1[j] + re[b]*V1[INNER + j] + c1[j];
        }
        __syncthreads();
        int flat = (bid - 24)*256 + tid;    // = b*256 + j
        int b = flat >> 8, j = flat & 255;
        float acc = c2[j];
        #pragma unroll 4
        for (int kk = 0; kk < INNER; ++kk)
            acc = fmaf(in_s[b*INNER + kk], V2[kk*INNER + j], acc);
        s2h[flat] = (_Float16)acc;
    }
}

static __device__ inline unsigned pk2(float a, float b) {
    auto t = __builtin_amdgcn_cvt_pkrtz(a, b);   // __fp16 ext_vector(2)
    return __builtin_bit_cast(unsigned, t);
}

// MFMA hypernet GEMM: wave = 64 cols, B-frags gathered from global f32 W
// (dword), cvt_pkrtz -> f16x8, mfma 16x16x32, no LDS/barriers, 2-deep pipeline.
#define LOADT(S, t) \
    _Pragma("unroll") for (int cc = 0; cc < 4; ++cc) { \
        _Pragma("unroll") for (int j = 0; j < 8; ++j) \
            S[cc*8+j] = Wp[(size_t)((t)*32 + g*8 + j)*NC + cc*16]; }

#define COMPT(S, t) \
    _Pragma("unroll") for (int cc = 0; cc < 4; ++cc) { \
        union { unsigned u[4]; f16x8 v; } bf; \
        bf.u[0] = pk2(S[cc*8+0], S[cc*8+1]); \
        bf.u[1] = pk2(S[cc*8+2], S[cc*8+3]); \
        bf.u[2] = pk2(S[cc*8+4], S[cc*8+5]); \
        bf.u[3] = pk2(S[cc*8+6], S[cc*8+7]); \
        acc[cc] = __builtin_amdgcn_mfma_f32_16x16x32_f16(af[(t)], bf.v, acc[cc], 0, 0, 0); }

template<int K, int NC, int KSG>
__device__ __forceinline__ void hgemm_body(int bidl, int tid,
                                           const _Float16* __restrict__ th,
                                           const float* __restrict__ W,
                                           float* __restrict__ partial)
{
    constexpr int KR = K / KSG;       // 192 (W3) or 64 (V3)
    constexpr int TILES = KR / 32;    // 6 or 2 (even)
    constexpr int NCB = NC / 256;
    int w = tid >> 6, lane = tid & 63;
    int ql = lane & 15, g = lane >> 4;
    int cb = bidl % NCB, ksg = bidl / NCB;
    int colbase = cb*256 + w*64;
    const float* Wp = W + (size_t)(ksg*KR)*NC + colbase + ql;

    f16x8 af[TILES];
    #pragma unroll
    for (int t = 0; t < TILES; ++t)
        af[t] = *(const f16x8*)(th + ql*K + ksg*KR + t*32 + g*8);

    f32x4 acc[4];
    #pragma unroll
    for (int cc = 0; cc < 4; ++cc) acc[cc] = (f32x4){0.f, 0.f, 0.f, 0.f};

    float sA[32], sB[32];
    LOADT(sA, 0)
    LOADT(sB, 1)
    #pragma unroll
    for (int t = 0; t < TILES; t += 2) {
        COMPT(sA, t)
        if (t + 2 < TILES) LOADT(sA, t+2)
        COMPT(sB, t+1)
        if (t + 3 < TILES) LOADT(sB, t+3)
    }

    float* pp = partial + (size_t)ksg*B*NC + colbase + ql;
    #pragma unroll
    for (int cc = 0; cc < 4; ++cc)
        #pragma unroll
        for (int r = 0; r < 4; ++r)
            pp[(size_t)(4*g + r)*NC + cc*16] = acc[cc][r];
}

#define NBH ((NC_H/256)*2)   /* 768 */
#define NBO ((NC_O/256)*4)   /* 512 */

__global__ __launch_bounds__(256) void k_hgemm_all(const _Float16* __restrict__ t2h,
                                                   const _Float16* __restrict__ s2h,
                                                   const float* __restrict__ W3,
                                                   const float* __restrict__ V3,
                                                   float* __restrict__ pH,
                                                   float* __restrict__ pO)
{
    int bid = blockIdx.x, tid = threadIdx.x;
    if (bid < NBH) hgemm_body<D3, NC_H, 2>(bid, tid, t2h, W3, pH);
    else           hgemm_body<INNER, NC_O, 4>(bid - NBH, tid, s2h, V3, pO);
}

// ---- fused split-K reduce + bias + column softmax (optional transposed fp16 out) ----
template<int R, int CPB, int COLS, int GROUPS, int KSG, int NC, bool TR, typename OT>
__device__ __forceinline__ void smred_body(int bidl, int tid,
                                           const float* __restrict__ partial,
                                           const float* __restrict__ bias,
                                           OT* __restrict__ outp,
                                           float* __restrict__ red)
{
    constexpr int RPT = R / GROUPS;
    int col = tid % COLS, g = tid / COLS;
    constexpr int nb = CPB / COLS;
    int b = bidl / nb, cb = bidl % nb;
    int e = cb*COLS + col;
    float vals[RPT];
    float m = -1e30f;
    #pragma unroll 4
    for (int r = 0; r < RPT; ++r) {
        int flat = (g*RPT + r)*CPB + e;
        float s = bias[flat];
        #pragma unroll
        for (int ks = 0; ks < KSG; ++ks)
            s += partial[(size_t)ks*B*NC + (size_t)b*NC + flat];
        vals[r] = s;
        m = fmaxf(m, s);
    }
    red[g*COLS + col] = m;
    __syncthreads();
    float M = red[col];
    #pragma unroll
    for (int gg = 1; gg < GROUPS; ++gg) M = fmaxf(M, red[gg*COLS + col]);
    __syncthreads();
    float s = 0.f;
    #pragma unroll 4
    for (int r = 0; r < RPT; ++r) { vals[r] = __expf(vals[r] - M); s += vals[r]; }
    red[g*COLS + col] = s;
    __syncthreads();
    float S = 0.f;
    #pragma unroll
    for (int gg = 0; gg < GROUPS; ++gg) S += red[gg*COLS + col];
    float inv = 1.f / S;
    #pragma unroll 4
    for (int r = 0; r < RPT; ++r) {
        if constexpr (TR)
            outp[(size_t)b*NC + (size_t)e*R + (g*RPT + r)] = (OT)(vals[r] * inv);
        else
            outp[(size_t)b*NC + (size_t)(g*RPT + r)*CPB + e] = (OT)(vals[r] * inv);
    }
}

#define NSH (B*24)   /* 384: h path  (R=128 over d, CPB=768) -> hh fp16 [e][d] */
#define NSO (B*8)    /* 128: ow path (R=256 over e, CPB=128) -> ow f32 */

__global__ __launch_bounds__(256) void k_smred(const float* __restrict__ pH,
                                               const float* __restrict__ pO,
                                               const float* __restrict__ b3,
                                               const float* __restrict__ c3,
                                               _Float16* __restrict__ hh,
                                               float* __restrict__ ow)
{
    __shared__ float red[256];
    int bid = blockIdx.x, tid = threadIdx.x;
    if (bid < NSH) smred_body<DIM, 3*INNER, 32, 8, 2, NC_H, true, _Float16>(bid, tid, pH, b3, hh, red);
    else           smred_body<INNER, DIM, 16, 16, 4, NC_O, false, float>(bid - NSH, tid, pO, c3, ow, red);
}

// ---- MFMA projection; x loaded f32 and converted in-register (RNE) ----
__global__ __launch_bounds__(256) void k_projm(const float* __restrict__ x,
                                               const _Float16* __restrict__ hh,
                                               _Float16* __restrict__ qh,
                                               _Float16* __restrict__ kh,
                                               _Float16* __restrict__ vt)
{
    int bid = blockIdx.x;               // 16 b x 38 chunks
    int b = bid / 38, cn = bid % 38;
    int n0 = cn * 16;
    int tid = threadIdx.x;
    int w = tid >> 6, lane = tid & 63;
    int ql = lane & 15, g = lane >> 4;

    const float* xb = x + (size_t)b*N*DIM;
    const _Float16* hb = hh + (size_t)b*NC_H;

    int nl = n0 + ql; if (nl > 599) nl = 599;
    f16x8 xf[4];
    #pragma unroll
    for (int kt = 0; kt < 4; ++kt) {
        float4 a = *(const float4*)(xb + (size_t)nl*DIM + kt*32 + g*8);
        float4 c = *(const float4*)(xb + (size_t)nl*DIM + kt*32 + g*8 + 4);
        union { _Float16 hv[8]; f16x8 v; } cv;
        cv.hv[0] = (_Float16)a.x; cv.hv[1] = (_Float16)a.y;
        cv.hv[2] = (_Float16)a.z; cv.hv[3] = (_Float16)a.w;
        cv.hv[4] = (_Float16)c.x; cv.hv[5] = (_Float16)c.y;
        cv.hv[6] = (_Float16)c.z; cv.hv[7] = (_Float16)c.w;
        xf[kt] = cv.v;
    }

    const float scale = 0.17677669529663687f;   // 32^-0.5 folded into q
    #pragma unroll
    for (int j = 0; j < 12; ++j) {
        int ct = w*12 + j;              // 0..47
        int type = ct >> 4;             // 0=q, 1=k, 2=v
        int e0 = (ct & 15) * 16;        // col base within its 256-group
        f16x8 wf[4];
        #pragma unroll
        for (int kt = 0; kt < 4; ++kt)
            wf[kt] = *(const f16x8*)(hb + (size_t)(ct*16 + ql)*DIM + kt*32 + g*8);
        f32x4 acc = (f32x4){0.f, 0.f, 0.f, 0.f};
        if (type == 2) {
            #pragma unroll
            for (int kt = 0; kt < 4; ++kt)
                acc = __builtin_amdgcn_mfma_f32_16x16x32_f16(wf[kt], xf[kt], acc, 0, 0, 0);
            int n = n0 + ql;
            if (n < 600) {
                #pragma unroll
                for (int r = 0; r < 4; ++r) {
                    int e = e0 + 4*g + r;
                    vt[((size_t)(b*HEADS + (e>>5))*DH + (e&31))*640 + n] = (_Float16)acc[r];
                }
            }
        } else {
            #pragma unroll
            for (int kt = 0; kt < 4; ++kt)
                acc = __builtin_amdgcn_mfma_f32_16x16x32_f16(xf[kt], wf[kt], acc, 0, 0, 0);
            int e = e0 + ql;
            int head = e >> 5, dh = e & 31;
            _Float16* dst = (type == 0 ? qh : kh);
            float scl = (type == 0) ? scale : 1.f;
            #pragma unroll
            for (int r = 0; r < 4; ++r) {
                int n = n0 + 4*g + r;
                if (n < 600)
                    dst[((size_t)(b*HEADS + head)*N + n)*DH + dh] = (_Float16)(acc[r]*scl);
            }
        }
    }
    // vt tail cols 600..639: zero-fill (0*NaN = NaN hazard in PV otherwise)
    if (cn == 37) {
        _Float16* vp = vt + ((size_t)b*256 + tid)*640;
        #pragma unroll
        for (int c = 600; c < 640; ++c) vp[c] = (_Float16)0.f;
    }
}

// MFMA flash attention v4b.  Same 4-wave structure as the proven v4; ONLY the
// grid decode changes: hg = (bid%32)>>4, b = bid%16 -> the two blocks sharing
// a (b,qc) mask tile are 16 apart (16 % 8 == 0: SAME XCD -> mask L2-shared),
// and per-XCD K/V working set drops to 2 b's (~2.4MB < 4MB L2).
// ao output is fp16 (saves 10MB round-trip; error washes out in k_final avg).
__global__ __launch_bounds__(256) void k_attn4(const _Float16* __restrict__ qh,
                                               const _Float16* __restrict__ kh,
                                               const _Float16* __restrict__ vt,
                                               const float* __restrict__ mask,
                                               _Float16* __restrict__ ao)
{
    __shared__ float mbuf[2][16][65];
    __shared__ __align__(16) _Float16 plds[4][16][72];
    int bid = blockIdx.x;
    int qc = bid / 32, r2 = bid % 32;
    int hg = r2 >> 4, b = r2 & 15;
    int tid = threadIdx.x;
    int w = tid >> 6, lane = tid & 63;
    int ql = lane & 15, g = lane >> 4;
    int h = hg*4 + w;
    int q0 = qc*16;
    size_t bh = (size_t)(b*HEADS + h);
    const _Float16* Qb  = qh + bh*(size_t)(N*DH);
    const _Float16* Kb  = kh + bh*(size_t)(N*DH);
    const _Float16* Vtb = vt + bh*(size_t)(DH*640);

    int qrow = q0 + ql;
    int qr = qrow > 599 ? 599 : qrow;
    f16x8 qf = *(const f16x8*)(Qb + (size_t)qr*DH + g*8);

    int rl = w*4 + (lane >> 4);
    int mcol = (lane & 15)*4;
    int mgr = q0 + rl; if (mgr > 599) mgr = 599;
    const float* mgp = mask + ((size_t)b*N + mgr)*N;

    float M = -1e30f, S = 0.f;
    f32x4 acc[2];
    acc[0] = (f32x4){0.f,0.f,0.f,0.f};
    acc[1] = (f32x4){0.f,0.f,0.f,0.f};

    {
        int c0 = mcol; if (c0 > 596) c0 = 596;
        float4 mv = *(const float4*)(mgp + c0);
        mbuf[0][rl][mcol+0] = mv.x;
        mbuf[0][rl][mcol+1] = mv.y;
        mbuf[0][rl][mcol+2] = mv.z;
        mbuf[0][rl][mcol+3] = mv.w;
    }
    __syncthreads();

    for (int c = 0; c < 10; ++c) {
        int k0 = c*64;
        int cur = c & 1;
        float4 mnext;
        if (c < 9) {
            int cg = (c+1)*64 + mcol; if (cg > 596) cg = 596;
            mnext = *(const float4*)(mgp + cg);
        }
        f32x4 st[4];
        #pragma unroll
        for (int t = 0; t < 4; ++t) {
            int kr = k0 + 16*t + ql; if (kr > 599) kr = 599;
            f16x8 kf = *(const f16x8*)(Kb + (size_t)kr*DH + g*8);
            st[t] = __builtin_amdgcn_mfma_f32_16x16x32_f16(
                kf, qf, (f32x4){0.f,0.f,0.f,0.f}, 0, 0, 0);
        }
        float tm = -1e30f;
        #pragma unroll
        for (int t = 0; t < 4; ++t) {
            #pragma unroll
            for (int r = 0; r < 4; ++r) {
                int key = k0 + 16*t + 4*g + r;
                float sv = st[t][r];
                if (key >= N) sv = -1e30f;
                st[t][r] = sv;
                tm = fmaxf(tm, sv);
            }
        }
        tm = fmaxf(tm, __shfl_xor(tm, 16));
        tm = fmaxf(tm, __shfl_xor(tm, 32));
        float Mn = fmaxf(M, tm);
        float scl = __expf(M - Mn);
        M = Mn;
        S *= scl;
        acc[0] *= scl;
        acc[1] *= scl;
        float ssum = 0.f;
        #pragma unroll
        for (int t = 0; t < 4; ++t) {
            int cb4 = 16*t + 4*g;
            float e0 = __expf(st[t][0] - Mn);
            float e1 = __expf(st[t][1] - Mn);
            float e2 = __expf(st[t][2] - Mn);
            float e3 = __expf(st[t][3] - Mn);
            ssum += (e0 + e1) + (e2 + e3);
            float m0 = mbuf[cur][ql][cb4+0];
            float m1 = mbuf[cur][ql][cb4+1];
            float m2 = mbuf[cur][ql][cb4+2];
            float m3 = mbuf[cur][ql][cb4+3];
            *(unsigned*)&plds[w][ql][cb4]     = pk2(e0*m0, e1*m1);
            *(unsigned*)&plds[w][ql][cb4 + 2] = pk2(e2*m2, e3*m3);
        }
        ssum += __shfl_xor(ssum, 16);
        ssum += __shfl_xor(ssum, 32);
        S += ssum;
        #pragma unroll
        for (int win = 0; win < 2; ++win) {
            f16x8 pf = *(const f16x8*)&plds[w][ql][win*32 + g*8];
            #pragma unroll
            for (int dt = 0; dt < 2; ++dt) {
                f16x8 vf = *(const f16x8*)(Vtb + (size_t)(dt*16 + ql)*640 + k0 + win*32 + g*8);
                acc[dt] = __builtin_amdgcn_mfma_f32_16x16x32_f16(vf, pf, acc[dt], 0, 0, 0);
            }
        }
        if (c < 9) {
            int nb = cur ^ 1;
            mbuf[nb][rl][mcol+0] = mnext.x;
            mbuf[nb][rl][mcol+1] = mnext.y;
            mbuf[nb][rl][mcol+2] = mnext.z;
            mbuf[nb][rl][mcol+3] = mnext.w;
        }
        __syncthreads();
    }

    if (qrow < N) {
        float inv = 1.f / S;
        _Float16* o = ao + ((size_t)b*N + qrow)*INNER + h*DH;
        #pragma unroll
        for (int dt = 0; dt < 2; ++dt) {
            union { _Float16 h4[4]; unsigned u2[2]; } pkv;
            #pragma unroll
            for (int r = 0; r < 4; ++r) pkv.h4[r] = (_Float16)(acc[dt][r] * inv);
            *(uint2*)(o + dt*16 + 4*g) = *(uint2*)pkv.u2;   // 8B-aligned
        }
    }
}

__global__ __launch_bounds__(128) void k_final(const _Float16* __restrict__ ao,
                                               const float* __restrict__ ow,
                                               float* __restrict__ out)
{
    __shared__ float4 os4[6*64];
    int b = blockIdx.x / 100, t0 = (blockIdx.x % 100)*6;
    int tid = threadIdx.x;
    const f16x8* ap8 = (const f16x8*)(ao + ((size_t)b*N + t0)*INNER);
    for (int i = tid; i < 6*32; i += 128) {     // 6 rows x 256 = 192 f16x8 chunks
        f16x8 v = ap8[i];
        os4[2*i]     = make_float4((float)v[0], (float)v[1], (float)v[2], (float)v[3]);
        os4[2*i + 1] = make_float4((float)v[4], (float)v[5], (float)v[6], (float)v[7]);
    }
    __syncthreads();
    float acc[6];
    #pragma unroll
    for (int r = 0; r < 6; ++r) acc[r] = 0.f;
    const float* wp = ow + (size_t)b*NC_O + tid;
    for (int i4 = 0; i4 < 64; ++i4) {
        float w0 = wp[(size_t)(4*i4)*DIM];
        float w1 = wp[(size_t)(4*i4+1)*DIM];
        float w2 = wp[(size_t)(4*i4+2)*DIM];
        float w3 = wp[(size_t)(4*i4+3)*DIM];
        #pragma unroll
        for (int r = 0; r < 6; ++r) {
            float4 av = os4[r*64 + i4];
            acc[r] = fmaf(av.x, w0, fmaf(av.y, w1, fmaf(av.z, w2, fmaf(av.w, w3, acc[r]))));
        }
    }
    float* op = out + ((size_t)b*N + t0)*DIM + tid;
    #pragma unroll
    for (int r = 0; r < 6; ++r) op[r*DIM] = acc[r];
}

extern "C" void kernel_launch(void* const* d_in, const int* in_sizes, int n_in,
                              void* d_out, int out_size, void* d_ws, size_t ws_size,
                              hipStream_t stream)
{
    const float* x          = (const float*)d_in[0];
    const float* mask       = (const float*)d_in[1];
    const float* resolution = (const float*)d_in[2];
    const float* framerate  = (const float*)d_in[3];
    const float* W1 = (const float*)d_in[4];
    const float* b1 = (const float*)d_in[5];
    const float* W2 = (const float*)d_in[6];
    const float* b2 = (const float*)d_in[7];
    const float* W3 = (const float*)d_in[8];
    const float* b3 = (const float*)d_in[9];
    const float* V1 = (const float*)d_in[10];
    const float* c1 = (const float*)d_in[11];
    const float* V2 = (const float*)d_in[12];
    const float* c2 = (const float*)d_in[13];
    const float* V3 = (const float*)d_in[14];
    const float* c3 = (const float*)d_in[15];

    float* ws = (float*)d_ws;
    _Float16* hh  = (_Float16*)(ws + 10240);     // [16][768][128]
    float* ow  = ws + 1583104;
    _Float16* ao  = (_Float16*)(ws + 2117632);   // [16][600][256] fp16
    _Float16* qh  = (_Float16*)(ws + 4575232);
    _Float16* kh  = (_Float16*)(ws + 5804032);
    _Float16* vt  = (_Float16*)(ws + 7032832);
    _Float16* t2h = (_Float16*)(ws + 8343552);   // [16][384]
    _Float16* s2h = (_Float16*)(ws + 8346624);   // [16][256]
    float* pH  = ws + 8963072;              // 2 x 1,572,864
    float* pO  = ws + 12108800;             // 4 x 524,288
    float* out = (float*)d_out;

    hipLaunchKernelGGL(k_chain, dim3(40), dim3(256), 0, stream,
                       resolution, framerate, W1, b1, W2, b2, V1, c1, V2, c2,
                       t2h, s2h);
    hipLaunchKernelGGL(k_hgemm_all, dim3(NBH + NBO), dim3(256), 0, stream,
                       t2h, s2h, W3, V3, pH, pO);
    hipLaunchKernelGGL(k_smred, dim3(NSH + NSO), dim3(256), 0, stream,
                       pH, pO, b3, c3, hh, ow);
    hipLaunchKernelGGL(k_projm, dim3(B*38), dim3(256), 0, stream,
                       x, hh, qh, kh, vt);
    hipLaunchKernelGGL(k_attn4, dim3(38*32), dim3(256), 0, stream, qh, kh, vt, mask, ao);
    hipLaunchKernelGGL(k_final, dim3(B*100), dim3(128), 0, stream, ao, ow, out);
}

// Round 16
// 156.846 us; speedup vs baseline: 1.0742x; 1.0175x over previous
//
#include <hip/hip_runtime.h>
#include <hip/hip_bf16.h>
#include <math.h>

#define B 16
#define N 600
#define DIM 128
#define HEADS 8
#define DH 32
#define INNER 256
#define D3 384
#define NC_H (D3*INNER)   /* 98304 */
#define NC_O (INNER*DIM)  /* 32768 */

typedef _Float16 f16x8 __attribute__((ext_vector_type(8)));
typedef float    f32x4 __attribute__((ext_vector_type(4)));

// ---------------- ws layout (float offsets) ----------------  ws = 576 MiB
// hh : 10240   (half, [16][768][128] qkvw softmaxed, TRANSPOSED [e][d])
// ow : 1583104 (f32,  [16][256][128])
// ao : 2117632 (half, [16][600][256])
// qh : 4575232(half)  kh : 5804032(half)  vt : 7032832(half)
// t2h: 8343552 (half, [16][384])   s2h: 8346624 (half, [16][256])
// pH : 8963072  (16 x 98304 f32, NO split-K)   pO : 10535936 (16 x 32768 f32)

// ---- fused hypernet layers 1+2 ----
__global__ __launch_bounds__(256) void k_chain(const float* __restrict__ resolution,
                                               const float* __restrict__ framerate,
                                               const float* __restrict__ W1, const float* __restrict__ b1,
                                               const float* __restrict__ W2, const float* __restrict__ b2,
                                               const float* __restrict__ V1, const float* __restrict__ c1,
                                               const float* __restrict__ V2, const float* __restrict__ c2,
                                               _Float16* __restrict__ t2h, _Float16* __restrict__ s2h)
{
    __shared__ float fr[B], re[B];
    __shared__ float in_s[B*D3];
    int bid = blockIdx.x, tid = threadIdx.x;
    if (tid < B) { fr[tid] = framerate[tid]; re[tid] = resolution[tid]; }
    __syncthreads();
    if (bid < 24) {
        for (int i = tid; i < B*D3; i += 256) {
            int b = i / D3, j = i - b*D3;
            in_s[i] = fr[b]*W1[j] + re[b]*W1[D3 + j] + b1[j];
        }
        __syncthreads();
        int flat = bid*256 + tid;           // = b*384 + j
        int b = flat / D3, j = flat - b*D3;
        float acc = b2[j];
        #pragma unroll 4
        for (int kk = 0; kk < D3; ++kk)
            acc = fmaf(in_s[b*D3 + kk], W2[kk*D3 + j], acc);
        t2h[flat] = (_Float16)acc;
    } else {
        for (int i = tid; i < B*INNER; i += 256) {
            int b = i >> 8, j = i & 255;
            in_s[i] = fr[b]*V1[j] + re[b]*V1[INNER + j] + c1[j];
        }
        __syncthreads();
        int flat = (bid - 24)*256 + tid;    // = b*256 + j
        int b = flat >> 8, j = flat & 255;
        float acc = c2[j];
        #pragma unroll 4
        for (int kk = 0; kk < INNER; ++kk)
            acc = fmaf(in_s[b*INNER + kk], V2[kk*INNER + j], acc);
        s2h[flat] = (_Float16)acc;
    }
}

static __device__ inline unsigned pk2(float a, float b) {
    auto t = __builtin_amdgcn_cvt_pkrtz(a, b);   // __fp16 ext_vector(2)
    return __builtin_bit_cast(unsigned, t);
}

// MFMA hypernet GEMM: wave = 64 cols over FULL K (no split-K); B-frags gathered
// from global f32 W (dword), cvt_pkrtz -> f16x8, mfma 16x16x32, no LDS/barriers,
// 2-deep register pipeline (64 outstanding dword loads/wave).
#define LOADT(S, t) \
    _Pragma("unroll") for (int cc = 0; cc < 4; ++cc) { \
        _Pragma("unroll") for (int j = 0; j < 8; ++j) \
            S[cc*8+j] = Wp[(size_t)((t)*32 + g*8 + j)*NC + cc*16]; }

#define COMPT(S, t) \
    _Pragma("unroll") for (int cc = 0; cc < 4; ++cc) { \
        union { unsigned u[4]; f16x8 v; } bf; \
        bf.u[0] = pk2(S[cc*8+0], S[cc*8+1]); \
        bf.u[1] = pk2(S[cc*8+2], S[cc*8+3]); \
        bf.u[2] = pk2(S[cc*8+4], S[cc*8+5]); \
        bf.u[3] = pk2(S[cc*8+6], S[cc*8+7]); \
        acc[cc] = __builtin_amdgcn_mfma_f32_16x16x32_f16(af[(t)], bf.v, acc[cc], 0, 0, 0); }

template<int K, int NC>
__device__ __forceinline__ void hgemm_body(int bidl, int tid,
                                           const _Float16* __restrict__ th,
                                           const float* __restrict__ W,
                                           float* __restrict__ outw)
{
    constexpr int TILES = K / 32;     // 12 (W3) or 8 (V3) — even
    int w = tid >> 6, lane = tid & 63;
    int ql = lane & 15, g = lane >> 4;
    int colbase = bidl*256 + w*64;
    const float* Wp = W + colbase + ql;

    f16x8 af[TILES];
    #pragma unroll
    for (int t = 0; t < TILES; ++t)
        af[t] = *(const f16x8*)(th + ql*K + t*32 + g*8);

    f32x4 acc[4];
    #pragma unroll
    for (int cc = 0; cc < 4; ++cc) acc[cc] = (f32x4){0.f, 0.f, 0.f, 0.f};

    float sA[32], sB[32];
    LOADT(sA, 0)
    LOADT(sB, 1)
    #pragma unroll
    for (int t = 0; t < TILES; t += 2) {
        COMPT(sA, t)
        if (t + 2 < TILES) LOADT(sA, t+2)
        COMPT(sB, t+1)
        if (t + 3 < TILES) LOADT(sB, t+3)
    }

    float* pp = outw + colbase + ql;
    #pragma unroll
    for (int cc = 0; cc < 4; ++cc)
        #pragma unroll
        for (int r = 0; r < 4; ++r)
            pp[(size_t)(4*g + r)*NC + cc*16] = acc[cc][r];
}

#define NBH (NC_H/256)   /* 384 */
#define NBO (NC_O/256)   /* 128 */

__global__ __launch_bounds__(256) void k_hgemm_all(const _Float16* __restrict__ t2h,
                                                   const _Float16* __restrict__ s2h,
                                                   const float* __restrict__ W3,
                                                   const float* __restrict__ V3,
                                                   float* __restrict__ pH,
                                                   float* __restrict__ pO)
{
    int bid = blockIdx.x, tid = threadIdx.x;
    if (bid < NBH) hgemm_body<D3, NC_H>(bid, tid, t2h, W3, pH);
    else           hgemm_body<INNER, NC_O>(bid - NBH, tid, s2h, V3, pO);
}

// ---- fused bias + column softmax (optional transposed fp16 out) ----
template<int R, int CPB, int COLS, int GROUPS, int NC, bool TR, typename OT>
__device__ __forceinline__ void smred_body(int bidl, int tid,
                                           const float* __restrict__ pre,
                                           const float* __restrict__ bias,
                                           OT* __restrict__ outp,
                                           float* __restrict__ red)
{
    constexpr int RPT = R / GROUPS;
    int col = tid % COLS, g = tid / COLS;
    constexpr int nb = CPB / COLS;
    int b = bidl / nb, cb = bidl % nb;
    int e = cb*COLS + col;
    float vals[RPT];
    float m = -1e30f;
    #pragma unroll 4
    for (int r = 0; r < RPT; ++r) {
        int flat = (g*RPT + r)*CPB + e;
        float s = bias[flat] + pre[(size_t)b*NC + flat];
        vals[r] = s;
        m = fmaxf(m, s);
    }
    red[g*COLS + col] = m;
    __syncthreads();
    float M = red[col];
    #pragma unroll
    for (int gg = 1; gg < GROUPS; ++gg) M = fmaxf(M, red[gg*COLS + col]);
    __syncthreads();
    float s = 0.f;
    #pragma unroll 4
    for (int r = 0; r < RPT; ++r) { vals[r] = __expf(vals[r] - M); s += vals[r]; }
    red[g*COLS + col] = s;
    __syncthreads();
    float S = 0.f;
    #pragma unroll
    for (int gg = 0; gg < GROUPS; ++gg) S += red[gg*COLS + col];
    float inv = 1.f / S;
    #pragma unroll 4
    for (int r = 0; r < RPT; ++r) {
        if constexpr (TR)
            outp[(size_t)b*NC + (size_t)e*R + (g*RPT + r)] = (OT)(vals[r] * inv);
        else
            outp[(size_t)b*NC + (size_t)(g*RPT + r)*CPB + e] = (OT)(vals[r] * inv);
    }
}

#define NSH (B*24)   /* 384: h path  (R=128 over d, CPB=768) -> hh fp16 [e][d] */
#define NSO (B*8)    /* 128: ow path (R=256 over e, CPB=128) -> ow f32 */

__global__ __launch_bounds__(256) void k_smred(const float* __restrict__ pH,
                                               const float* __restrict__ pO,
                                               const float* __restrict__ b3,
                                               const float* __restrict__ c3,
                                               _Float16* __restrict__ hh,
                                               float* __restrict__ ow)
{
    __shared__ float red[256];
    int bid = blockIdx.x, tid = threadIdx.x;
    if (bid < NSH) smred_body<DIM, 3*INNER, 32, 8, NC_H, true, _Float16>(bid, tid, pH, b3, hh, red);
    else           smred_body<INNER, DIM, 16, 16, NC_O, false, float>(bid - NSH, tid, pO, c3, ow, red);
}

// ---- MFMA projection; x loaded f32 and converted in-register (RNE) ----
__global__ __launch_bounds__(256) void k_projm(const float* __restrict__ x,
                                               const _Float16* __restrict__ hh,
                                               _Float16* __restrict__ qh,
                                               _Float16* __restrict__ kh,
                                               _Float16* __restrict__ vt)
{
    int bid = blockIdx.x;               // 16 b x 38 chunks
    int b = bid / 38, cn = bid % 38;
    int n0 = cn * 16;
    int tid = threadIdx.x;
    int w = tid >> 6, lane = tid & 63;
    int ql = lane & 15, g = lane >> 4;

    const float* xb = x + (size_t)b*N*DIM;
    const _Float16* hb = hh + (size_t)b*NC_H;

    int nl = n0 + ql; if (nl > 599) nl = 599;
    f16x8 xf[4];
    #pragma unroll
    for (int kt = 0; kt < 4; ++kt) {
        float4 a = *(const float4*)(xb + (size_t)nl*DIM + kt*32 + g*8);
        float4 c = *(const float4*)(xb + (size_t)nl*DIM + kt*32 + g*8 + 4);
        union { _Float16 hv[8]; f16x8 v; } cv;
        cv.hv[0] = (_Float16)a.x; cv.hv[1] = (_Float16)a.y;
        cv.hv[2] = (_Float16)a.z; cv.hv[3] = (_Float16)a.w;
        cv.hv[4] = (_Float16)c.x; cv.hv[5] = (_Float16)c.y;
        cv.hv[6] = (_Float16)c.z; cv.hv[7] = (_Float16)c.w;
        xf[kt] = cv.v;
    }

    const float scale = 0.17677669529663687f;   // 32^-0.5 folded into q
    #pragma unroll
    for (int j = 0; j < 12; ++j) {
        int ct = w*12 + j;              // 0..47
        int type = ct >> 4;             // 0=q, 1=k, 2=v
        int e0 = (ct & 15) * 16;        // col base within its 256-group
        f16x8 wf[4];
        #pragma unroll
        for (int kt = 0; kt < 4; ++kt)
            wf[kt] = *(const f16x8*)(hb + (size_t)(ct*16 + ql)*DIM + kt*32 + g*8);
        f32x4 acc = (f32x4){0.f, 0.f, 0.f, 0.f};
        if (type == 2) {
            #pragma unroll
            for (int kt = 0; kt < 4; ++kt)
                acc = __builtin_amdgcn_mfma_f32_16x16x32_f16(wf[kt], xf[kt], acc, 0, 0, 0);
            int n = n0 + ql;
            if (n < 600) {
                #pragma unroll
                for (int r = 0; r < 4; ++r) {
                    int e = e0 + 4*g + r;
                    vt[((size_t)(b*HEADS + (e>>5))*DH + (e&31))*640 + n] = (_Float16)acc[r];
                }
            }
        } else {
            #pragma unroll
            for (int kt = 0; kt < 4; ++kt)
                acc = __builtin_amdgcn_mfma_f32_16x16x32_f16(xf[kt], wf[kt], acc, 0, 0, 0);
            int e = e0 + ql;
            int head = e >> 5, dh = e & 31;
            _Float16* dst = (type == 0 ? qh : kh);
            float scl = (type == 0) ? scale : 1.f;
            #pragma unroll
            for (int r = 0; r < 4; ++r) {
                int n = n0 + 4*g + r;
                if (n < 600)
                    dst[((size_t)(b*HEADS + head)*N + n)*DH + dh] = (_Float16)(acc[r]*scl);
            }
        }
    }
    // vt tail cols 600..639: zero-fill (0*NaN = NaN hazard in PV otherwise)
    if (cn == 37) {
        _Float16* vp = vt + ((size_t)b*256 + tid)*640;
        #pragma unroll
        for (int c = 600; c < 640; ++c) vp[c] = (_Float16)0.f;
    }
}

// MFMA flash attention v4b (round-14/15 proven config).
__global__ __launch_bounds__(256) void k_attn4(const _Float16* __restrict__ qh,
                                               const _Float16* __restrict__ kh,
                                               const _Float16* __restrict__ vt,
                                               const float* __restrict__ mask,
                                               _Float16* __restrict__ ao)
{
    __shared__ float mbuf[2][16][65];
    __shared__ __align__(16) _Float16 plds[4][16][72];
    int bid = blockIdx.x;
    int qc = bid / 32, r2 = bid % 32;
    int hg = r2 >> 4, b = r2 & 15;
    int tid = threadIdx.x;
    int w = tid >> 6, lane = tid & 63;
    int ql = lane & 15, g = lane >> 4;
    int h = hg*4 + w;
    int q0 = qc*16;
    size_t bh = (size_t)(b*HEADS + h);
    const _Float16* Qb  = qh + bh*(size_t)(N*DH);
    const _Float16* Kb  = kh + bh*(size_t)(N*DH);
    const _Float16* Vtb = vt + bh*(size_t)(DH*640);

    int qrow = q0 + ql;
    int qr = qrow > 599 ? 599 : qrow;
    f16x8 qf = *(const f16x8*)(Qb + (size_t)qr*DH + g*8);

    int rl = w*4 + (lane >> 4);
    int mcol = (lane & 15)*4;
    int mgr = q0 + rl; if (mgr > 599) mgr = 599;
    const float* mgp = mask + ((size_t)b*N + mgr)*N;

    float M = -1e30f, S = 0.f;
    f32x4 acc[2];
    acc[0] = (f32x4){0.f,0.f,0.f,0.f};
    acc[1] = (f32x4){0.f,0.f,0.f,0.f};

    {
        int c0 = mcol; if (c0 > 596) c0 = 596;
        float4 mv = *(const float4*)(mgp + c0);
        mbuf[0][rl][mcol+0] = mv.x;
        mbuf[0][rl][mcol+1] = mv.y;
        mbuf[0][rl][mcol+2] = mv.z;
        mbuf[0][rl][mcol+3] = mv.w;
    }
    __syncthreads();

    for (int c = 0; c < 10; ++c) {
        int k0 = c*64;
        int cur = c & 1;
        float4 mnext;
        if (c < 9) {
            int cg = (c+1)*64 + mcol; if (cg > 596) cg = 596;
            mnext = *(const float4*)(mgp + cg);
        }
        f32x4 st[4];
        #pragma unroll
        for (int t = 0; t < 4; ++t) {
            int kr = k0 + 16*t + ql; if (kr > 599) kr = 599;
            f16x8 kf = *(const f16x8*)(Kb + (size_t)kr*DH + g*8);
            st[t] = __builtin_amdgcn_mfma_f32_16x16x32_f16(
                kf, qf, (f32x4){0.f,0.f,0.f,0.f}, 0, 0, 0);
        }
        float tm = -1e30f;
        #pragma unroll
        for (int t = 0; t < 4; ++t) {
            #pragma unroll
            for (int r = 0; r < 4; ++r) {
                int key = k0 + 16*t + 4*g + r;
                float sv = st[t][r];
                if (key >= N) sv = -1e30f;
                st[t][r] = sv;
                tm = fmaxf(tm, sv);
            }
        }
        tm = fmaxf(tm, __shfl_xor(tm, 16));
        tm = fmaxf(tm, __shfl_xor(tm, 32));
        float Mn = fmaxf(M, tm);
        float scl = __expf(M - Mn);
        M = Mn;
        S *= scl;
        acc[0] *= scl;
        acc[1] *= scl;
        float ssum = 0.f;
        #pragma unroll
        for (int t = 0; t < 4; ++t) {
            int cb4 = 16*t + 4*g;
            float e0 = __expf(st[t][0] - Mn);
            float e1 = __expf(st[t][1] - Mn);
            float e2 = __expf(st[t][2] - Mn);
            float e3 = __expf(st[t][3] - Mn);
            ssum += (e0 + e1) + (e2 + e3);
            float m0 = mbuf[cur][ql][cb4+0];
            float m1 = mbuf[cur][ql][cb4+1];
            float m2 = mbuf[cur][ql][cb4+2];
            float m3 = mbuf[cur][ql][cb4+3];
            *(unsigned*)&plds[w][ql][cb4]     = pk2(e0*m0, e1*m1);
            *(unsigned*)&plds[w][ql][cb4 + 2] = pk2(e2*m2, e3*m3);
        }
        ssum += __shfl_xor(ssum, 16);
        ssum += __shfl_xor(ssum, 32);
        S += ssum;
        #pragma unroll
        for (int win = 0; win < 2; ++win) {
            f16x8 pf = *(const f16x8*)&plds[w][ql][win*32 + g*8];
            #pragma unroll
            for (int dt = 0; dt < 2; ++dt) {
                f16x8 vf = *(const f16x8*)(Vtb + (size_t)(dt*16 + ql)*640 + k0 + win*32 + g*8);
                acc[dt] = __builtin_amdgcn_mfma_f32_16x16x32_f16(vf, pf, acc[dt], 0, 0, 0);
            }
        }
        if (c < 9) {
            int nb = cur ^ 1;
            mbuf[nb][rl][mcol+0] = mnext.x;
            mbuf[nb][rl][mcol+1] = mnext.y;
            mbuf[nb][rl][mcol+2] = mnext.z;
            mbuf[nb][rl][mcol+3] = mnext.w;
        }
        __syncthreads();
    }

    if (qrow < N) {
        float inv = 1.f / S;
        _Float16* o = ao + ((size_t)b*N + qrow)*INNER + h*DH;
        #pragma unroll
        for (int dt = 0; dt < 2; ++dt) {
            union { _Float16 h4[4]; unsigned u2[2]; } pkv;
            #pragma unroll
            for (int r = 0; r < 4; ++r) pkv.h4[r] = (_Float16)(acc[dt][r] * inv);
            *(uint2*)(o + dt*16 + 4*g) = *(uint2*)pkv.u2;   // 8B-aligned
        }
    }
}

__global__ __launch_bounds__(128) void k_final(const _Float16* __restrict__ ao,
                                               const float* __restrict__ ow,
                                               float* __restrict__ out)
{
    __shared__ float4 os4[6*64];
    int b = blockIdx.x / 100, t0 = (blockIdx.x % 100)*6;
    int tid = threadIdx.x;
    const f16x8* ap8 = (const f16x8*)(ao + ((size_t)b*N + t0)*INNER);
    for (int i = tid; i < 6*32; i += 128) {     // 6 rows x 256 = 192 f16x8 chunks
        f16x8 v = ap8[i];
        os4[2*i]     = make_float4((float)v[0], (float)v[1], (float)v[2], (float)v[3]);
        os4[2*i + 1] = make_float4((float)v[4], (float)v[5], (float)v[6], (float)v[7]);
    }
    __syncthreads();
    float acc[6];
    #pragma unroll
    for (int r = 0; r < 6; ++r) acc[r] = 0.f;
    const float* wp = ow + (size_t)b*NC_O + tid;
    for (int i4 = 0; i4 < 64; ++i4) {
        float w0 = wp[(size_t)(4*i4)*DIM];
        float w1 = wp[(size_t)(4*i4+1)*DIM];
        float w2 = wp[(size_t)(4*i4+2)*DIM];
        float w3 = wp[(size_t)(4*i4+3)*DIM];
        #pragma unroll
        for (int r = 0; r < 6; ++r) {
            float4 av = os4[r*64 + i4];
            acc[r] = fmaf(av.x, w0, fmaf(av.y, w1, fmaf(av.z, w2, fmaf(av.w, w3, acc[r]))));
        }
    }
    float* op = out + ((size_t)b*N + t0)*DIM + tid;
    #pragma unroll
    for (int r = 0; r < 6; ++r) op[r*DIM] = acc[r];
}

extern "C" void kernel_launch(void* const* d_in, const int* in_sizes, int n_in,
                              void* d_out, int out_size, void* d_ws, size_t ws_size,
                              hipStream_t stream)
{
    const float* x          = (const float*)d_in[0];
    const float* mask       = (const float*)d_in[1];
    const float* resolution = (const float*)d_in[2];
    const float* framerate  = (const float*)d_in[3];
    const float* W1 = (const float*)d_in[4];
    const float* b1 = (const float*)d_in[5];
    const float* W2 = (const float*)d_in[6];
    const float* b2 = (const float*)d_in[7];
    const float* W3 = (const float*)d_in[8];
    const float* b3 = (const float*)d_in[9];
    const float* V1 = (const float*)d_in[10];
    const float* c1 = (const float*)d_in[11];
    const float* V2 = (const float*)d_in[12];
    const float* c2 = (const float*)d_in[13];
    const float* V3 = (const float*)d_in[14];
    const float* c3 = (const float*)d_in[15];

    float* ws = (float*)d_ws;
    _Float16* hh  = (_Float16*)(ws + 10240);     // [16][768][128]
    float* ow  = ws + 1583104;
    _Float16* ao  = (_Float16*)(ws + 2117632);   // [16][600][256] fp16
    _Float16* qh  = (_Float16*)(ws + 4575232);
    _Float16* kh  = (_Float16*)(ws + 5804032);
    _Float16* vt  = (_Float16*)(ws + 7032832);
    _Float16* t2h = (_Float16*)(ws + 8343552);   // [16][384]
    _Float16* s2h = (_Float16*)(ws + 8346624);   // [16][256]
    float* pH  = ws + 8963072;              // 16 x 98304 (pre-softmax, no bias)
    float* pO  = ws + 10535936;             // 16 x 32768
    float* out = (float*)d_out;

    hipLaunchKernelGGL(k_chain, dim3(40), dim3(256), 0, stream,
                       resolution, framerate, W1, b1, W2, b2, V1, c1, V2, c2,
                       t2h, s2h);
    hipLaunchKernelGGL(k_hgemm_all, dim3(NBH + NBO), dim3(256), 0, stream,
                       t2h, s2h, W3, V3, pH, pO);
    hipLaunchKernelGGL(k_smred, dim3(NSH + NSO), dim3(256), 0, stream,
                       pH, pO, b3, c3, hh, ow);
    hipLaunchKernelGGL(k_projm, dim3(B*38), dim3(256), 0, stream,
                       x, hh, qh, kh, vt);
    hipLaunchKernelGGL(k_attn4, dim3(38*32), dim3(256), 0, stream, qh, kh, vt, mask, ao);
    hipLaunchKernelGGL(k_final, dim3(B*100), dim3(128), 0, stream, ao, ow, out);
}

// Round 17
// 154.722 us; speedup vs baseline: 1.0890x; 1.0137x over previous
//
#include <hip/hip_runtime.h>
#include <hip/hip_bf16.h>
#include <math.h>

#define B 16
#define N 600
#define DIM 128
#define HEADS 8
#define DH 32
#define INNER 256
#define D3 384
#define NC_H (D3*INNER)   /* 98304 */
#define NC_O (INNER*DIM)  /* 32768 */

typedef _Float16 f16x8 __attribute__((ext_vector_type(8)));
typedef float    f32x4 __attribute__((ext_vector_type(4)));

// ---------------- ws layout (float offsets) ----------------  ws = 576 MiB
// hh : 10240   (half, [16][768][128] qkvw softmaxed, TRANSPOSED [e][d])
// ow : 1583104 (f32,  [16][256][128])
// ao : 2117632 (half, [16][600][256])
// qh : 4575232(half)  kh : 5804032(half)  vt : 7032832(half)
// t2h: 8343552 (half, [16][384])   s2h: 8346624 (half, [16][256])
// pH : 8963072  (16 x 98304 f32, NO split-K)   pO : 10535936 (16 x 32768 f32)

// ---- fused hypernet layers 1+2 ----
__global__ __launch_bounds__(256) void k_chain(const float* __restrict__ resolution,
                                               const float* __restrict__ framerate,
                                               const float* __restrict__ W1, const float* __restrict__ b1,
                                               const float* __restrict__ W2, const float* __restrict__ b2,
                                               const float* __restrict__ V1, const float* __restrict__ c1,
                                               const float* __restrict__ V2, const float* __restrict__ c2,
                                               _Float16* __restrict__ t2h, _Float16* __restrict__ s2h)
{
    __shared__ float fr[B], re[B];
    __shared__ float in_s[B*D3];
    int bid = blockIdx.x, tid = threadIdx.x;
    if (tid < B) { fr[tid] = framerate[tid]; re[tid] = resolution[tid]; }
    __syncthreads();
    if (bid < 24) {
        for (int i = tid; i < B*D3; i += 256) {
            int b = i / D3, j = i - b*D3;
            in_s[i] = fr[b]*W1[j] + re[b]*W1[D3 + j] + b1[j];
        }
        __syncthreads();
        int flat = bid*256 + tid;           // = b*384 + j
        int b = flat / D3, j = flat - b*D3;
        float acc = b2[j];
        #pragma unroll 4
        for (int kk = 0; kk < D3; ++kk)
            acc = fmaf(in_s[b*D3 + kk], W2[kk*D3 + j], acc);
        t2h[flat] = (_Float16)acc;
    } else {
        for (int i = tid; i < B*INNER; i += 256) {
            int b = i >> 8, j = i & 255;
            in_s[i] = fr[b]*V1[j] + re[b]*V1[INNER + j] + c1[j];
        }
        __syncthreads();
        int flat = (bid - 24)*256 + tid;    // = b*256 + j
        int b = flat >> 8, j = flat & 255;
        float acc = c2[j];
        #pragma unroll 4
        for (int kk = 0; kk < INNER; ++kk)
            acc = fmaf(in_s[b*INNER + kk], V2[kk*INNER + j], acc);
        s2h[flat] = (_Float16)acc;
    }
}

static __device__ inline unsigned pk2(float a, float b) {
    auto t = __builtin_amdgcn_cvt_pkrtz(a, b);   // __fp16 ext_vector(2)
    return __builtin_bit_cast(unsigned, t);
}

// MFMA hypernet GEMM: wave = 64 cols over FULL K; B-frags gathered from global
// f32 W (dword), cvt_pkrtz -> f16x8, mfma 16x16x32, no LDS/barriers.
// FOUR-deep register pipeline (sA..sD): ~16KB/wave in flight across stalls.
#define LOADT(S, t) \
    _Pragma("unroll") for (int cc = 0; cc < 4; ++cc) { \
        _Pragma("unroll") for (int j = 0; j < 8; ++j) \
            S[cc*8+j] = Wp[(size_t)((t)*32 + g*8 + j)*NC + cc*16]; }

#define COMPT(S, t) \
    _Pragma("unroll") for (int cc = 0; cc < 4; ++cc) { \
        union { unsigned u[4]; f16x8 v; } bf; \
        bf.u[0] = pk2(S[cc*8+0], S[cc*8+1]); \
        bf.u[1] = pk2(S[cc*8+2], S[cc*8+3]); \
        bf.u[2] = pk2(S[cc*8+4], S[cc*8+5]); \
        bf.u[3] = pk2(S[cc*8+6], S[cc*8+7]); \
        acc[cc] = __builtin_amdgcn_mfma_f32_16x16x32_f16(af[(t)], bf.v, acc[cc], 0, 0, 0); }

template<int K, int NC>
__device__ __forceinline__ void hgemm_body(int bidl, int tid,
                                           const _Float16* __restrict__ th,
                                           const float* __restrict__ W,
                                           float* __restrict__ outw)
{
    constexpr int TILES = K / 32;     // 12 (W3) or 8 (V3) — divisible by 4
    static_assert(TILES % 4 == 0, "4-deep pipeline needs TILES % 4 == 0");
    int w = tid >> 6, lane = tid & 63;
    int ql = lane & 15, g = lane >> 4;
    int colbase = bidl*256 + w*64;
    const float* Wp = W + colbase + ql;

    f16x8 af[TILES];
    #pragma unroll
    for (int t = 0; t < TILES; ++t)
        af[t] = *(const f16x8*)(th + ql*K + t*32 + g*8);

    f32x4 acc[4];
    #pragma unroll
    for (int cc = 0; cc < 4; ++cc) acc[cc] = (f32x4){0.f, 0.f, 0.f, 0.f};

    float sA[32], sB[32], sC[32], sD[32];
    LOADT(sA, 0)
    LOADT(sB, 1)
    LOADT(sC, 2)
    LOADT(sD, 3)
    #pragma unroll
    for (int t = 0; t < TILES; t += 4) {
        COMPT(sA, t)
        if (t + 4 < TILES) LOADT(sA, t+4)
        COMPT(sB, t+1)
        if (t + 5 < TILES) LOADT(sB, t+5)
        COMPT(sC, t+2)
        if (t + 6 < TILES) LOADT(sC, t+6)
        COMPT(sD, t+3)
        if (t + 7 < TILES) LOADT(sD, t+7)
    }

    float* pp = outw + colbase + ql;
    #pragma unroll
    for (int cc = 0; cc < 4; ++cc)
        #pragma unroll
        for (int r = 0; r < 4; ++r)
            pp[(size_t)(4*g + r)*NC + cc*16] = acc[cc][r];
}

#define NBH (NC_H/256)   /* 384 */
#define NBO (NC_O/256)   /* 128 */

__global__ __launch_bounds__(256) void k_hgemm_all(const _Float16* __restrict__ t2h,
                                                   const _Float16* __restrict__ s2h,
                                                   const float* __restrict__ W3,
                                                   const float* __restrict__ V3,
                                                   float* __restrict__ pH,
                                                   float* __restrict__ pO)
{
    int bid = blockIdx.x, tid = threadIdx.x;
    if (bid < NBH) hgemm_body<D3, NC_H>(bid, tid, t2h, W3, pH);
    else           hgemm_body<INNER, NC_O>(bid - NBH, tid, s2h, V3, pO);
}

// ---- fused bias + column softmax (optional transposed fp16 out) ----
template<int R, int CPB, int COLS, int GROUPS, int NC, bool TR, typename OT>
__device__ __forceinline__ void smred_body(int bidl, int tid,
                                           const float* __restrict__ pre,
                                           const float* __restrict__ bias,
                                           OT* __restrict__ outp,
                                           float* __restrict__ red)
{
    constexpr int RPT = R / GROUPS;
    int col = tid % COLS, g = tid / COLS;
    constexpr int nb = CPB / COLS;
    int b = bidl / nb, cb = bidl % nb;
    int e = cb*COLS + col;
    float vals[RPT];
    float m = -1e30f;
    #pragma unroll 4
    for (int r = 0; r < RPT; ++r) {
        int flat = (g*RPT + r)*CPB + e;
        float s = bias[flat] + pre[(size_t)b*NC + flat];
        vals[r] = s;
        m = fmaxf(m, s);
    }
    red[g*COLS + col] = m;
    __syncthreads();
    float M = red[col];
    #pragma unroll
    for (int gg = 1; gg < GROUPS; ++gg) M = fmaxf(M, red[gg*COLS + col]);
    __syncthreads();
    float s = 0.f;
    #pragma unroll 4
    for (int r = 0; r < RPT; ++r) { vals[r] = __expf(vals[r] - M); s += vals[r]; }
    red[g*COLS + col] = s;
    __syncthreads();
    float S = 0.f;
    #pragma unroll
    for (int gg = 0; gg < GROUPS; ++gg) S += red[gg*COLS + col];
    float inv = 1.f / S;
    #pragma unroll 4
    for (int r = 0; r < RPT; ++r) {
        if constexpr (TR)
            outp[(size_t)b*NC + (size_t)e*R + (g*RPT + r)] = (OT)(vals[r] * inv);
        else
            outp[(size_t)b*NC + (size_t)(g*RPT + r)*CPB + e] = (OT)(vals[r] * inv);
    }
}

#define NSH (B*24)   /* 384: h path  (R=128 over d, CPB=768) -> hh fp16 [e][d] */
#define NSO (B*8)    /* 128: ow path (R=256 over e, CPB=128) -> ow f32 */

__global__ __launch_bounds__(256) void k_smred(const float* __restrict__ pH,
                                               const float* __restrict__ pO,
                                               const float* __restrict__ b3,
                                               const float* __restrict__ c3,
                                               _Float16* __restrict__ hh,
                                               float* __restrict__ ow)
{
    __shared__ float red[256];
    int bid = blockIdx.x, tid = threadIdx.x;
    if (bid < NSH) smred_body<DIM, 3*INNER, 32, 8, NC_H, true, _Float16>(bid, tid, pH, b3, hh, red);
    else           smred_body<INNER, DIM, 16, 16, NC_O, false, float>(bid - NSH, tid, pO, c3, ow, red);
}

// ---- MFMA projection; x loaded f32 and converted in-register (RNE) ----
__global__ __launch_bounds__(256) void k_projm(const float* __restrict__ x,
                                               const _Float16* __restrict__ hh,
                                               _Float16* __restrict__ qh,
                                               _Float16* __restrict__ kh,
                                               _Float16* __restrict__ vt)
{
    int bid = blockIdx.x;               // 16 b x 38 chunks
    int b = bid / 38, cn = bid % 38;
    int n0 = cn * 16;
    int tid = threadIdx.x;
    int w = tid >> 6, lane = tid & 63;
    int ql = lane & 15, g = lane >> 4;

    const float* xb = x + (size_t)b*N*DIM;
    const _Float16* hb = hh + (size_t)b*NC_H;

    int nl = n0 + ql; if (nl > 599) nl = 599;
    f16x8 xf[4];
    #pragma unroll
    for (int kt = 0; kt < 4; ++kt) {
        float4 a = *(const float4*)(xb + (size_t)nl*DIM + kt*32 + g*8);
        float4 c = *(const float4*)(xb + (size_t)nl*DIM + kt*32 + g*8 + 4);
        union { _Float16 hv[8]; f16x8 v; } cv;
        cv.hv[0] = (_Float16)a.x; cv.hv[1] = (_Float16)a.y;
        cv.hv[2] = (_Float16)a.z; cv.hv[3] = (_Float16)a.w;
        cv.hv[4] = (_Float16)c.x; cv.hv[5] = (_Float16)c.y;
        cv.hv[6] = (_Float16)c.z; cv.hv[7] = (_Float16)c.w;
        xf[kt] = cv.v;
    }

    const float scale = 0.17677669529663687f;   // 32^-0.5 folded into q
    #pragma unroll
    for (int j = 0; j < 12; ++j) {
        int ct = w*12 + j;              // 0..47
        int type = ct >> 4;             // 0=q, 1=k, 2=v
        int e0 = (ct & 15) * 16;        // col base within its 256-group
        f16x8 wf[4];
        #pragma unroll
        for (int kt = 0; kt < 4; ++kt)
            wf[kt] = *(const f16x8*)(hb + (size_t)(ct*16 + ql)*DIM + kt*32 + g*8);
        f32x4 acc = (f32x4){0.f, 0.f, 0.f, 0.f};
        if (type == 2) {
            #pragma unroll
            for (int kt = 0; kt < 4; ++kt)
                acc = __builtin_amdgcn_mfma_f32_16x16x32_f16(wf[kt], xf[kt], acc, 0, 0, 0);
            int n = n0 + ql;
            if (n < 600) {
                #pragma unroll
                for (int r = 0; r < 4; ++r) {
                    int e = e0 + 4*g + r;
                    vt[((size_t)(b*HEADS + (e>>5))*DH + (e&31))*640 + n] = (_Float16)acc[r];
                }
            }
        } else {
            #pragma unroll
            for (int kt = 0; kt < 4; ++kt)
                acc = __builtin_amdgcn_mfma_f32_16x16x32_f16(xf[kt], wf[kt], acc, 0, 0, 0);
            int e = e0 + ql;
            int head = e >> 5, dh = e & 31;
            _Float16* dst = (type == 0 ? qh : kh);
            float scl = (type == 0) ? scale : 1.f;
            #pragma unroll
            for (int r = 0; r < 4; ++r) {
                int n = n0 + 4*g + r;
                if (n < 600)
                    dst[((size_t)(b*HEADS + head)*N + n)*DH + dh] = (_Float16)(acc[r]*scl);
            }
        }
    }
    // vt tail cols 600..639: zero-fill (0*NaN = NaN hazard in PV otherwise)
    if (cn == 37) {
        _Float16* vp = vt + ((size_t)b*256 + tid)*640;
        #pragma unroll
        for (int c = 600; c < 640; ++c) vp[c] = (_Float16)0.f;
    }
}

// MFMA flash attention v4b (round-14/15 proven config).
__global__ __launch_bounds__(256) void k_attn4(const _Float16* __restrict__ qh,
                                               const _Float16* __restrict__ kh,
                                               const _Float16* __restrict__ vt,
                                               const float* __restrict__ mask,
                                               _Float16* __restrict__ ao)
{
    __shared__ float mbuf[2][16][65];
    __shared__ __align__(16) _Float16 plds[4][16][72];
    int bid = blockIdx.x;
    int qc = bid / 32, r2 = bid % 32;
    int hg = r2 >> 4, b = r2 & 15;
    int tid = threadIdx.x;
    int w = tid >> 6, lane = tid & 63;
    int ql = lane & 15, g = lane >> 4;
    int h = hg*4 + w;
    int q0 = qc*16;
    size_t bh = (size_t)(b*HEADS + h);
    const _Float16* Qb  = qh + bh*(size_t)(N*DH);
    const _Float16* Kb  = kh + bh*(size_t)(N*DH);
    const _Float16* Vtb = vt + bh*(size_t)(DH*640);

    int qrow = q0 + ql;
    int qr = qrow > 599 ? 599 : qrow;
    f16x8 qf = *(const f16x8*)(Qb + (size_t)qr*DH + g*8);

    int rl = w*4 + (lane >> 4);
    int mcol = (lane & 15)*4;
    int mgr = q0 + rl; if (mgr > 599) mgr = 599;
    const float* mgp = mask + ((size_t)b*N + mgr)*N;

    float M = -1e30f, S = 0.f;
    f32x4 acc[2];
    acc[0] = (f32x4){0.f,0.f,0.f,0.f};
    acc[1] = (f32x4){0.f,0.f,0.f,0.f};

    {
        int c0 = mcol; if (c0 > 596) c0 = 596;
        float4 mv = *(const float4*)(mgp + c0);
        mbuf[0][rl][mcol+0] = mv.x;
        mbuf[0][rl][mcol+1] = mv.y;
        mbuf[0][rl][mcol+2] = mv.z;
        mbuf[0][rl][mcol+3] = mv.w;
    }
    __syncthreads();

    for (int c = 0; c < 10; ++c) {
        int k0 = c*64;
        int cur = c & 1;
        float4 mnext;
        if (c < 9) {
            int cg = (c+1)*64 + mcol; if (cg > 596) cg = 596;
            mnext = *(const float4*)(mgp + cg);
        }
        f32x4 st[4];
        #pragma unroll
        for (int t = 0; t < 4; ++t) {
            int kr = k0 + 16*t + ql; if (kr > 599) kr = 599;
            f16x8 kf = *(const f16x8*)(Kb + (size_t)kr*DH + g*8);
            st[t] = __builtin_amdgcn_mfma_f32_16x16x32_f16(
                kf, qf, (f32x4){0.f,0.f,0.f,0.f}, 0, 0, 0);
        }
        float tm = -1e30f;
        #pragma unroll
        for (int t = 0; t < 4; ++t) {
            #pragma unroll
            for (int r = 0; r < 4; ++r) {
                int key = k0 + 16*t + 4*g + r;
                float sv = st[t][r];
                if (key >= N) sv = -1e30f;
                st[t][r] = sv;
                tm = fmaxf(tm, sv);
            }
        }
        tm = fmaxf(tm, __shfl_xor(tm, 16));
        tm = fmaxf(tm, __shfl_xor(tm, 32));
        float Mn = fmaxf(M, tm);
        float scl = __expf(M - Mn);
        M = Mn;
        S *= scl;
        acc[0] *= scl;
        acc[1] *= scl;
        float ssum = 0.f;
        #pragma unroll
        for (int t = 0; t < 4; ++t) {
            int cb4 = 16*t + 4*g;
            float e0 = __expf(st[t][0] - Mn);
            float e1 = __expf(st[t][1] - Mn);
            float e2 = __expf(st[t][2] - Mn);
            float e3 = __expf(st[t][3] - Mn);
            ssum += (e0 + e1) + (e2 + e3);
            float m0 = mbuf[cur][ql][cb4+0];
            float m1 = mbuf[cur][ql][cb4+1];
            float m2 = mbuf[cur][ql][cb4+2];
            float m3 = mbuf[cur][ql][cb4+3];
            *(unsigned*)&plds[w][ql][cb4]     = pk2(e0*m0, e1*m1);
            *(unsigned*)&plds[w][ql][cb4 + 2] = pk2(e2*m2, e3*m3);
        }
        ssum += __shfl_xor(ssum, 16);
        ssum += __shfl_xor(ssum, 32);
        S += ssum;
        #pragma unroll
        for (int win = 0; win < 2; ++win) {
            f16x8 pf = *(const f16x8*)&plds[w][ql][win*32 + g*8];
            #pragma unroll
            for (int dt = 0; dt < 2; ++dt) {
                f16x8 vf = *(const f16x8*)(Vtb + (size_t)(dt*16 + ql)*640 + k0 + win*32 + g*8);
                acc[dt] = __builtin_amdgcn_mfma_f32_16x16x32_f16(vf, pf, acc[dt], 0, 0, 0);
            }
        }
        if (c < 9) {
            int nb = cur ^ 1;
            mbuf[nb][rl][mcol+0] = mnext.x;
            mbuf[nb][rl][mcol+1] = mnext.y;
            mbuf[nb][rl][mcol+2] = mnext.z;
            mbuf[nb][rl][mcol+3] = mnext.w;
        }
        __syncthreads();
    }

    if (qrow < N) {
        float inv = 1.f / S;
        _Float16* o = ao + ((size_t)b*N + qrow)*INNER + h*DH;
        #pragma unroll
        for (int dt = 0; dt < 2; ++dt) {
            union { _Float16 h4[4]; unsigned u2[2]; } pkv;
            #pragma unroll
            for (int r = 0; r < 4; ++r) pkv.h4[r] = (_Float16)(acc[dt][r] * inv);
            *(uint2*)(o + dt*16 + 4*g) = *(uint2*)pkv.u2;   // 8B-aligned
        }
    }
}

__global__ __launch_bounds__(128) void k_final(const _Float16* __restrict__ ao,
                                               const float* __restrict__ ow,
                                               float* __restrict__ out)
{
    __shared__ float4 os4[6*64];
    int b = blockIdx.x / 100, t0 = (blockIdx.x % 100)*6;
    int tid = threadIdx.x;
    const f16x8* ap8 = (const f16x8*)(ao + ((size_t)b*N + t0)*INNER);
    for (int i = tid; i < 6*32; i += 128) {     // 6 rows x 256 = 192 f16x8 chunks
        f16x8 v = ap8[i];
        os4[2*i]     = make_float4((float)v[0], (float)v[1], (float)v[2], (float)v[3]);
        os4[2*i + 1] = make_float4((float)v[4], (float)v[5], (float)v[6], (float)v[7]);
    }
    __syncthreads();
    float acc[6];
    #pragma unroll
    for (int r = 0; r < 6; ++r) acc[r] = 0.f;
    const float* wp = ow + (size_t)b*NC_O + tid;
    for (int i4 = 0; i4 < 64; ++i4) {
        float w0 = wp[(size_t)(4*i4)*DIM];
        float w1 = wp[(size_t)(4*i4+1)*DIM];
        float w2 = wp[(size_t)(4*i4+2)*DIM];
        float w3 = wp[(size_t)(4*i4+3)*DIM];
        #pragma unroll
        for (int r = 0; r < 6; ++r) {
            float4 av = os4[r*64 + i4];
            acc[r] = fmaf(av.x, w0, fmaf(av.y, w1, fmaf(av.z, w2, fmaf(av.w, w3, acc[r]))));
        }
    }
    float* op = out + ((size_t)b*N + t0)*DIM + tid;
    #pragma unroll
    for (int r = 0; r < 6; ++r) op[r*DIM] = acc[r];
}

extern "C" void kernel_launch(void* const* d_in, const int* in_sizes, int n_in,
                              void* d_out, int out_size, void* d_ws, size_t ws_size,
                              hipStream_t stream)
{
    const float* x          = (const float*)d_in[0];
    const float* mask       = (const float*)d_in[1];
    const float* resolution = (const float*)d_in[2];
    const float* framerate  = (const float*)d_in[3];
    const float* W1 = (const float*)d_in[4];
    const float* b1 = (const float*)d_in[5];
    const float* W2 = (const float*)d_in[6];
    const float* b2 = (const float*)d_in[7];
    const float* W3 = (const float*)d_in[8];
    const float* b3 = (const float*)d_in[9];
    const float* V1 = (const float*)d_in[10];
    const float* c1 = (const float*)d_in[11];
    const float* V2 = (const float*)d_in[12];
    const float* c2 = (const float*)d_in[13];
    const float* V3 = (const float*)d_in[14];
    const float* c3 = (const float*)d_in[15];

    float* ws = (float*)d_ws;
    _Float16* hh  = (_Float16*)(ws + 10240);     // [16][768][128]
    float* ow  = ws + 1583104;
    _Float16* ao  = (_Float16*)(ws + 2117632);   // [16][600][256] fp16
    _Float16* qh  = (_Float16*)(ws + 4575232);
    _Float16* kh  = (_Float16*)(ws + 5804032);
    _Float16* vt  = (_Float16*)(ws + 7032832);
    _Float16* t2h = (_Float16*)(ws + 8343552);   // [16][384]
    _Float16* s2h = (_Float16*)(ws + 8346624);   // [16][256]
    float* pH  = ws + 8963072;              // 16 x 98304 (pre-softmax, no bias)
    float* pO  = ws + 10535936;             // 16 x 32768
    float* out = (float*)d_out;

    hipLaunchKernelGGL(k_chain, dim3(40), dim3(256), 0, stream,
                       resolution, framerate, W1, b1, W2, b2, V1, c1, V2, c2,
                       t2h, s2h);
    hipLaunchKernelGGL(k_hgemm_all, dim3(NBH + NBO), dim3(256), 0, stream,
                       t2h, s2h, W3, V3, pH, pO);
    hipLaunchKernelGGL(k_smred, dim3(NSH + NSO), dim3(256), 0, stream,
                       pH, pO, b3, c3, hh, ow);
    hipLaunchKernelGGL(k_projm, dim3(B*38), dim3(256), 0, stream,
                       x, hh, qh, kh, vt);
    hipLaunchKernelGGL(k_attn4, dim3(38*32), dim3(256), 0, stream, qh, kh, vt, mask, ao);
    hipLaunchKernelGGL(k_final, dim3(B*100), dim3(128), 0, stream, ao, ow, out);
}